// Round 1
// baseline (784.199 us; speedup 1.0000x reference)
//
#include <hip/hip_runtime.h>
#include <cstddef>

#define NN 10000  // N_NODES

__device__ __forceinline__ float lrelu(float x) { return x >= 0.f ? x : 0.01f * x; }

__device__ __forceinline__ void acc_edge(float4& acc, float4 z, float4 zn, float4 bb) {
  acc.x += lrelu(0.5f * (z.x + zn.x) + bb.x);
  acc.y += lrelu(0.5f * (z.y + zn.y) + bb.y);
  acc.z += lrelu(0.5f * (z.z + zn.z) + bb.z);
  acc.w += lrelu(0.5f * (z.w + zn.w) + bb.w);
}

// ---------------- CSR build ----------------
__global__ __launch_bounds__(256) void count_kernel(const int* __restrict__ dst,
                                                    int* __restrict__ degi, int E) {
  int e = blockIdx.x * 256 + threadIdx.x;
  if (e < E) atomicAdd(&degi[dst[e]], 1);
}

__global__ __launch_bounds__(256) void scan_rdeg_kernel(const int* __restrict__ degi,
                                                        int* __restrict__ off,
                                                        float* __restrict__ rdeg, int n) {
  __shared__ int wsum[4];
  __shared__ int wpre[4];
  __shared__ int carry_s;
  const int tid = threadIdx.x;
  const int lane = tid & 63, w = tid >> 6;
  if (tid == 0) carry_s = 0;
  __syncthreads();
  for (int base = 0; base < n; base += 256) {
    int i = base + tid;
    int x = (i < n) ? degi[i] : 0;
    int v = x;
#pragma unroll
    for (int d = 1; d < 64; d <<= 1) {
      int t = __shfl_up(v, d);
      if (lane >= d) v += t;
    }
    if (lane == 63) wsum[w] = v;
    __syncthreads();
    if (tid == 0) {
      int s = carry_s;
#pragma unroll
      for (int j = 0; j < 4; ++j) { int t = wsum[j]; wpre[j] = s; s += t; }
      carry_s = s;
    }
    __syncthreads();
    if (i < n) {
      off[i] = wpre[w] + (v - x);                  // exclusive prefix
      rdeg[i] = 1.0f / fmaxf((float)x, 1.0f);      // 1/max(deg,1)
    }
    __syncthreads();
  }
}

__global__ __launch_bounds__(256) void fill_kernel(const int* __restrict__ src,
                                                   const int* __restrict__ dst,
                                                   const int* __restrict__ off,
                                                   int* __restrict__ cursor,
                                                   int* __restrict__ eid_s,
                                                   int* __restrict__ esrc_s, int E) {
  int e = blockIdx.x * 256 + threadIdx.x;
  if (e < E) {
    int d = dst[e];
    int p = off[d] + atomicAdd(&cursor[d], 1);
    eid_s[p] = e;
    esrc_s[p] = src[e];
  }
}

// -------- wave-per-node segment gather-sum, 128 feats (float2/lane) --------
__global__ __launch_bounds__(256) void seg_gather128_kernel(
    const float* __restrict__ feat, const int* __restrict__ gidx,
    const int* __restrict__ off, const int* __restrict__ degi,
    const float* __restrict__ rdeg /* null -> no scale */, float* __restrict__ outfeat) {
  const int n = (blockIdx.x << 2) + (threadIdx.x >> 6);
  const int lane = threadIdx.x & 63;
  const int o = off[n], d = degi[n];
  float ax = 0.f, ay = 0.f;
  for (int c0 = 0; c0 < d; c0 += 64) {
    const int m = min(64, d - c0);
    const int g = (lane < m) ? gidx[o + c0 + lane] : 0;
    int i = 0;
    for (; i + 4 <= m; i += 4) {
      int s0 = __shfl(g, i), s1 = __shfl(g, i + 1), s2 = __shfl(g, i + 2), s3 = __shfl(g, i + 3);
      float2 v0 = *(const float2*)&feat[(size_t)s0 * 128 + (lane << 1)];
      float2 v1 = *(const float2*)&feat[(size_t)s1 * 128 + (lane << 1)];
      float2 v2 = *(const float2*)&feat[(size_t)s2 * 128 + (lane << 1)];
      float2 v3 = *(const float2*)&feat[(size_t)s3 * 128 + (lane << 1)];
      ax += v0.x + v1.x + v2.x + v3.x;
      ay += v0.y + v1.y + v2.y + v3.y;
    }
    for (; i < m; ++i) {
      int s0 = __shfl(g, i);
      float2 v0 = *(const float2*)&feat[(size_t)s0 * 128 + (lane << 1)];
      ax += v0.x; ay += v0.y;
    }
  }
  const float sc = rdeg ? rdeg[n] : 1.0f;
  float2 r; r.x = ax * sc; r.y = ay * sc;
  *(float2*)&outfeat[(size_t)n * 128 + (lane << 1)] = r;
}

// -------- wave-per-node segment gather-sum, 256 feats (float4/lane) --------
__global__ __launch_bounds__(256) void seg_gather256_kernel(
    const float* __restrict__ feat, const int* __restrict__ gidx,
    const int* __restrict__ off, const int* __restrict__ degi,
    float* __restrict__ outfeat) {
  const int n = (blockIdx.x << 2) + (threadIdx.x >> 6);
  const int lane = threadIdx.x & 63;
  const int o = off[n], d = degi[n];
  float4 acc = make_float4(0.f, 0.f, 0.f, 0.f);
  for (int c0 = 0; c0 < d; c0 += 64) {
    const int m = min(64, d - c0);
    const int g = (lane < m) ? gidx[o + c0 + lane] : 0;
    int i = 0;
    for (; i + 2 <= m; i += 2) {
      int s0 = __shfl(g, i), s1 = __shfl(g, i + 1);
      float4 z0 = *(const float4*)&feat[(size_t)s0 * 256 + (lane << 2)];
      float4 z1 = *(const float4*)&feat[(size_t)s1 * 256 + (lane << 2)];
      acc.x += z0.x + z1.x; acc.y += z0.y + z1.y;
      acc.z += z0.z + z1.z; acc.w += z0.w + z1.w;
    }
    for (; i < m; ++i) {
      int s0 = __shfl(g, i);
      float4 z0 = *(const float4*)&feat[(size_t)s0 * 256 + (lane << 2)];
      acc.x += z0.x; acc.y += z0.y; acc.z += z0.z; acc.w += z0.w;
    }
  }
  *(float4*)&outfeat[(size_t)n * 256 + (lane << 2)] = acc;
}

// -------- pass C: hB[n] = rdeg[n] * sum_e LR(0.5*(Z[src]+Z[n]) + b) --------
__global__ __launch_bounds__(256) void passC_kernel(
    const float* __restrict__ Z, const int* __restrict__ esrc,
    const int* __restrict__ off, const int* __restrict__ degi,
    const float* __restrict__ rdeg, const float* __restrict__ bias,
    float* __restrict__ hB) {
  const int n = (blockIdx.x << 2) + (threadIdx.x >> 6);
  const int lane = threadIdx.x & 63;
  const int o = off[n], d = degi[n];
  const float4 zn = *(const float4*)&Z[(size_t)n * 256 + (lane << 2)];
  const float4 bb = *(const float4*)&bias[lane << 2];
  float4 acc = make_float4(0.f, 0.f, 0.f, 0.f);
  for (int c0 = 0; c0 < d; c0 += 64) {
    const int m = min(64, d - c0);
    const int g = (lane < m) ? esrc[o + c0 + lane] : 0;
    int i = 0;
    for (; i + 2 <= m; i += 2) {
      int s0 = __shfl(g, i), s1 = __shfl(g, i + 1);
      float4 z0 = *(const float4*)&Z[(size_t)s0 * 256 + (lane << 2)];
      float4 z1 = *(const float4*)&Z[(size_t)s1 * 256 + (lane << 2)];
      acc_edge(acc, z0, zn, bb);
      acc_edge(acc, z1, zn, bb);
    }
    for (; i < m; ++i) {
      int s0 = __shfl(g, i);
      float4 z0 = *(const float4*)&Z[(size_t)s0 * 256 + (lane << 2)];
      acc_edge(acc, z0, zn, bb);
    }
  }
  const float r = rdeg[n];
  float4 outv = make_float4(acc.x * r, acc.y * r, acc.z * r, acc.w * r);
  *(float4*)&hB[(size_t)n * 256 + (lane << 2)] = outv;
}

// -------- pass E: partial per-block sums of LR(0.5*(Z2[src]+Z2[n]) + b) over all edges --------
__global__ __launch_bounds__(256) void passE_kernel(
    const float* __restrict__ Z2, const int* __restrict__ esrc,
    const int* __restrict__ off, const int* __restrict__ degi,
    const float* __restrict__ bias, float* __restrict__ partials, int nNodes) {
  const int lane = threadIdx.x & 63, w = threadIdx.x >> 6;
  const int gw = blockIdx.x * 4 + w, nw = gridDim.x * 4;
  const float4 bb = *(const float4*)&bias[lane << 2];
  float4 acc = make_float4(0.f, 0.f, 0.f, 0.f);
  for (int n = gw; n < nNodes; n += nw) {
    const int o = off[n], d = degi[n];
    const float4 zn = *(const float4*)&Z2[(size_t)n * 256 + (lane << 2)];
    for (int c0 = 0; c0 < d; c0 += 64) {
      const int m = min(64, d - c0);
      const int g = (lane < m) ? esrc[o + c0 + lane] : 0;
      int i = 0;
      for (; i + 2 <= m; i += 2) {
        int s0 = __shfl(g, i), s1 = __shfl(g, i + 1);
        float4 z0 = *(const float4*)&Z2[(size_t)s0 * 256 + (lane << 2)];
        float4 z1 = *(const float4*)&Z2[(size_t)s1 * 256 + (lane << 2)];
        acc_edge(acc, z0, zn, bb);
        acc_edge(acc, z1, zn, bb);
      }
      for (; i < m; ++i) {
        int s0 = __shfl(g, i);
        float4 z0 = *(const float4*)&Z2[(size_t)s0 * 256 + (lane << 2)];
        acc_edge(acc, z0, zn, bb);
      }
    }
  }
  __shared__ float red[4][256];
  *(float4*)&red[w][lane << 2] = acc;
  __syncthreads();
  if (w == 0) {
    float4 s0 = *(const float4*)&red[0][lane << 2];
    float4 s1 = *(const float4*)&red[1][lane << 2];
    float4 s2 = *(const float4*)&red[2][lane << 2];
    float4 s3 = *(const float4*)&red[3][lane << 2];
    float4 s = make_float4(s0.x + s1.x + s2.x + s3.x, s0.y + s1.y + s2.y + s3.y,
                           s0.z + s1.z + s2.z + s3.z, s0.w + s1.w + s2.w + s3.w);
    *(float4*)&partials[(size_t)blockIdx.x * 256 + (lane << 2)] = s;
  }
}

__global__ __launch_bounds__(256) void reduce_partials_kernel(const float* __restrict__ partials,
                                                              int nparts, float* __restrict__ macc) {
  const int f = threadIdx.x;  // 256
  float s = 0.f;
  for (int b = 0; b < nparts; ++b) s += partials[(size_t)b * 256 + f];
  macc[f] = s;
}

// -------- GEMM: C[n][o] = sum_k A[n][k] * W[o][k], O = 256 fixed --------
template <int K>
__global__ __launch_bounds__(256) void gemm_nt_kernel(const float* __restrict__ A,
                                                      const float* __restrict__ W,
                                                      float* __restrict__ C, int N) {
  __shared__ float As[16][68];
  __shared__ float Ws[16][68];
  const int bn = blockIdx.x * 64;
  const int bo = blockIdx.y * 64;
  const int tid = threadIdx.x;
  const int ln = tid >> 2;         // 0..63 load row
  const int lk = (tid & 3) << 2;   // 0,4,8,12 load k
  const int tn = (tid & 15) << 2;  // micro-tile node
  const int to = (tid >> 4) << 2;  // micro-tile out
  float acc[4][4] = {};
  for (int k0 = 0; k0 < K; k0 += 16) {
    float4 a = make_float4(0.f, 0.f, 0.f, 0.f);
    if (bn + ln < N) a = *(const float4*)&A[(size_t)(bn + ln) * K + k0 + lk];
    const float4 wl = *(const float4*)&W[(size_t)(bo + ln) * K + k0 + lk];
    As[lk + 0][ln] = a.x; As[lk + 1][ln] = a.y; As[lk + 2][ln] = a.z; As[lk + 3][ln] = a.w;
    Ws[lk + 0][ln] = wl.x; Ws[lk + 1][ln] = wl.y; Ws[lk + 2][ln] = wl.z; Ws[lk + 3][ln] = wl.w;
    __syncthreads();
#pragma unroll
    for (int kk = 0; kk < 16; ++kk) {
      float4 av = *(const float4*)&As[kk][tn];
      float4 wv = *(const float4*)&Ws[kk][to];
      float aarr[4] = {av.x, av.y, av.z, av.w};
      float warr[4] = {wv.x, wv.y, wv.z, wv.w};
#pragma unroll
      for (int i = 0; i < 4; ++i)
#pragma unroll
        for (int j = 0; j < 4; ++j) acc[i][j] = fmaf(aarr[i], warr[j], acc[i][j]);
    }
    __syncthreads();
  }
#pragma unroll
  for (int i = 0; i < 4; ++i) {
    const int n = bn + tn + i;
    if (n < NN) {
      float4 outv = make_float4(acc[i][0], acc[i][1], acc[i][2], acc[i][3]);
      *(float4*)&C[(size_t)n * 256 + bo + to] = outv;
    }
  }
}

// -------- final: out[j] = b3[j] + invE * sum_k macc[k] * W3[j][k] --------
__global__ __launch_bounds__(256) void final_kernel(const float* __restrict__ macc1,
                                                    const float* __restrict__ macc2,
                                                    const float* __restrict__ W3,
                                                    const float* __restrict__ b3,
                                                    float* __restrict__ out, float invE) {
  __shared__ float red[4][64];
  const int j = threadIdx.x & 63, part = threadIdx.x >> 6;
  float acc = 0.f;
  for (int kk = 0; kk < 128; ++kk) {
    const int k = part * 128 + kk;
    const float mv = (k < 256) ? macc1[k] : macc2[k - 256];
    acc += mv * W3[(size_t)j * 512 + k];
  }
  red[part][j] = acc;
  __syncthreads();
  if (part == 0)
    out[j] = b3[j] + (red[0][j] + red[1][j] + red[2][j] + red[3][j]) * invE;
}

extern "C" void kernel_launch(void* const* d_in, const int* in_sizes, int n_in,
                              void* d_out, int out_size, void* d_ws, size_t ws_size,
                              hipStream_t stream) {
  const float* in1 = (const float*)d_in[0];
  const int* src1 = (const int*)d_in[1];
  const int* dst1 = (const int*)d_in[2];
  const float* in2 = (const float*)d_in[3];
  const int* src2 = (const int*)d_in[4];
  const int* dst2 = (const int*)d_in[5];
  const float* W11 = (const float*)d_in[6];
  const float* b11 = (const float*)d_in[7];
  const float* W12 = (const float*)d_in[8];
  const float* b12 = (const float*)d_in[9];
  const float* W21 = (const float*)d_in[10];
  const float* b21 = (const float*)d_in[11];
  const float* W22 = (const float*)d_in[12];
  const float* b22 = (const float*)d_in[13];
  const float* W3 = (const float*)d_in[14];
  const float* b3 = (const float*)d_in[15];
  const int E = in_sizes[1];
  const int N = NN;

  // ---- workspace carve (512B aligned) ----
  char* base = (char*)d_ws;
  size_t pos = 0;
  auto carve = [&](size_t bytes) -> char* {
    char* p = base + pos;
    pos = (pos + bytes + 511) & ~(size_t)511;
    return p;
  };
  int* degcur = (int*)carve((size_t)2 * N * sizeof(int));  // [deg | cursor]
  int* degi = degcur;
  int* cursor = degcur + N;
  int* off = (int*)carve((size_t)N * sizeof(int));
  float* rdeg = (float*)carve((size_t)N * sizeof(float));
  int* eid_s = (int*)carve((size_t)E * sizeof(int));
  int* esrc_s = (int*)carve((size_t)E * sizeof(int));
  float* C256 = (float*)carve((size_t)N * 256 * sizeof(float));  // h | Z | Z2
  float* D256 = (float*)carve((size_t)N * 256 * sizeof(float));  // h2 | hB
  float* E256 = (float*)carve((size_t)N * 256 * sizeof(float));  // h2B
  float* partials = (float*)carve((size_t)256 * 256 * sizeof(float));
  float* macc1 = (float*)carve(256 * sizeof(float));
  float* macc2 = (float*)carve(256 * sizeof(float));
  (void)ws_size; (void)n_in; (void)out_size;

  const int EB = (E + 255) / 256;      // edge-parallel blocks
  const int NB = N / 4;                // wave-per-node blocks (4 waves/block)
  const dim3 gemm_grid((N + 63) / 64, 4);

  for (int g = 0; g < 2; ++g) {
    const float* inp = g ? in2 : in1;
    const int* src = g ? src2 : src1;
    const int* dst = g ? dst2 : dst1;
    const float* Wa = g ? W21 : W11;
    const float* ba = g ? b21 : b11;
    const float* Wb = g ? W22 : W12;
    const float* bb = g ? b22 : b12;
    float* macc = g ? macc2 : macc1;

    hipMemsetAsync(degcur, 0, (size_t)2 * N * sizeof(int), stream);
    count_kernel<<<EB, 256, 0, stream>>>(dst, degi, E);
    scan_rdeg_kernel<<<1, 256, 0, stream>>>(degi, off, rdeg, N);
    fill_kernel<<<EB, 256, 0, stream>>>(src, dst, off, cursor, eid_s, esrc_s, E);

    // layer 1: h = segsum(inputs, dst)/deg ; h2 = segsum(h[src], dst) ; Z = h2 @ Wa.T
    seg_gather128_kernel<<<NB, 256, 0, stream>>>(inp, eid_s, off, degi, rdeg, C256);
    seg_gather128_kernel<<<NB, 256, 0, stream>>>(C256, esrc_s, off, degi, nullptr, D256);
    gemm_nt_kernel<128><<<gemm_grid, 256, 0, stream>>>(D256, Wa, C256, N);

    // layer 2 input: hB = rdeg * segsum(LR(0.5*(Z[src]+Z[dst])+ba), dst)
    passC_kernel<<<NB, 256, 0, stream>>>(C256, esrc_s, off, degi, rdeg, ba, D256);
    // h2B = segsum(hB[src], dst) ; Z2 = h2B @ Wb.T
    seg_gather256_kernel<<<NB, 256, 0, stream>>>(D256, esrc_s, off, degi, E256);
    gemm_nt_kernel<256><<<gemm_grid, 256, 0, stream>>>(E256, Wb, C256, N);

    // mean over edges of LR(0.5*(Z2[src]+Z2[dst])+bb)  (unscaled sum -> macc)
    passE_kernel<<<256, 256, 0, stream>>>(C256, esrc_s, off, degi, bb, partials, N);
    reduce_partials_kernel<<<1, 256, 0, stream>>>(partials, 256, macc);
  }

  final_kernel<<<1, 256, 0, stream>>>(macc1, macc2, W3, b3, (float*)d_out, 1.0f / (float)E);
}

// Round 2
// 667.300 us; speedup vs baseline: 1.1752x; 1.1752x over previous
//
#include <hip/hip_runtime.h>
#include <cstddef>

#define NN 10000  // N_NODES

typedef unsigned int u32;

__device__ __forceinline__ float lrelu(float x) { return x >= 0.f ? x : 0.01f * x; }

// ---- bf16 helpers (tables stored bf16, math in f32) ----
__device__ __forceinline__ float bf_lo(u32 v) { union { u32 i; float f; } c; c.i = v << 16; return c.f; }
__device__ __forceinline__ float bf_hi(u32 v) { union { u32 i; float f; } c; c.i = v & 0xFFFF0000u; return c.f; }
__device__ __forceinline__ u32 rne_bits(float f) {
  union { float f; u32 i; } c; c.f = f;
  return c.i + 0x7FFFu + ((c.i >> 16) & 1u);
}
__device__ __forceinline__ u32 pack2(float a, float b) {
  return (rne_bits(a) >> 16) | (rne_bits(b) & 0xFFFF0000u);
}

__device__ __forceinline__ void acc_bf(float4& acc, uint2 v, const float4& zn, const float4& bb) {
  acc.x += lrelu(0.5f * (bf_lo(v.x) + zn.x) + bb.x);
  acc.y += lrelu(0.5f * (bf_hi(v.x) + zn.y) + bb.y);
  acc.z += lrelu(0.5f * (bf_lo(v.y) + zn.z) + bb.z);
  acc.w += lrelu(0.5f * (bf_hi(v.y) + zn.w) + bb.w);
}

// ---------------- CSR build ----------------
__global__ __launch_bounds__(256) void count_kernel(const int* __restrict__ dst,
                                                    int* __restrict__ degi, int E) {
  int e = blockIdx.x * 256 + threadIdx.x;
  if (e < E) atomicAdd(&degi[dst[e]], 1);
}

__global__ __launch_bounds__(1024) void scan_rdeg_kernel(const int* __restrict__ degi,
                                                         int* __restrict__ off,
                                                         float* __restrict__ rdeg, int n) {
  __shared__ int wsum[16];
  __shared__ int wpre[16];
  __shared__ int carry_s;
  const int tid = threadIdx.x;
  const int lane = tid & 63, w = tid >> 6;
  if (tid == 0) carry_s = 0;
  __syncthreads();
  for (int base = 0; base < n; base += 1024) {
    int i = base + tid;
    int x = (i < n) ? degi[i] : 0;
    int v = x;
#pragma unroll
    for (int d = 1; d < 64; d <<= 1) {
      int t = __shfl_up(v, d);
      if (lane >= d) v += t;
    }
    if (lane == 63) wsum[w] = v;
    __syncthreads();
    if (tid == 0) {
      int s = carry_s;
#pragma unroll
      for (int j = 0; j < 16; ++j) { int t = wsum[j]; wpre[j] = s; s += t; }
      carry_s = s;
    }
    __syncthreads();
    if (i < n) {
      off[i] = wpre[w] + (v - x);                  // exclusive prefix
      rdeg[i] = 1.0f / fmaxf((float)x, 1.0f);      // 1/max(deg,1)
    }
    __syncthreads();
  }
}

__global__ __launch_bounds__(256) void fill_kernel(const int* __restrict__ src,
                                                   const int* __restrict__ dst,
                                                   const int* __restrict__ off,
                                                   int* __restrict__ cursor,
                                                   int* __restrict__ eid_s,
                                                   int* __restrict__ esrc_s, int E) {
  int e = blockIdx.x * 256 + threadIdx.x;
  if (e < E) {
    int d = dst[e];
    int p = off[d] + atomicAdd(&cursor[d], 1);
    eid_s[p] = e;
    esrc_s[p] = src[e];
  }
}

// -------- pass A: h[n] = rdeg * segsum(inputs[eid], dst); f32 in -> bf16 out (128 feats) --------
__global__ __launch_bounds__(256) void gatherA_kernel(
    const float* __restrict__ feat, const int* __restrict__ gidx,
    const int* __restrict__ off, const int* __restrict__ degi,
    const float* __restrict__ rdeg, u32* __restrict__ outbf /* [N*64] */) {
  const int n = (blockIdx.x << 2) + (threadIdx.x >> 6);
  const int lane = threadIdx.x & 63;
  const int o = off[n], d = degi[n];
  float ax = 0.f, ay = 0.f;
  for (int c0 = 0; c0 < d; c0 += 64) {
    const int m = min(64, d - c0);
    const int g = (lane < m) ? gidx[o + c0 + lane] : 0;
    int i = 0;
    for (; i + 4 <= m; i += 4) {
      int s0 = __shfl(g, i), s1 = __shfl(g, i + 1), s2 = __shfl(g, i + 2), s3 = __shfl(g, i + 3);
      float2 v0 = *(const float2*)&feat[(size_t)s0 * 128 + (lane << 1)];
      float2 v1 = *(const float2*)&feat[(size_t)s1 * 128 + (lane << 1)];
      float2 v2 = *(const float2*)&feat[(size_t)s2 * 128 + (lane << 1)];
      float2 v3 = *(const float2*)&feat[(size_t)s3 * 128 + (lane << 1)];
      ax += v0.x + v1.x + v2.x + v3.x;
      ay += v0.y + v1.y + v2.y + v3.y;
    }
    for (; i < m; ++i) {
      int s0 = __shfl(g, i);
      float2 v0 = *(const float2*)&feat[(size_t)s0 * 128 + (lane << 1)];
      ax += v0.x; ay += v0.y;
    }
  }
  const float sc = rdeg[n];
  outbf[(size_t)n * 64 + lane] = pack2(ax * sc, ay * sc);
}

// -------- pass B: h2[n] = segsum(h[src]); bf16 table (128 feats) -> bf16 out --------
__global__ __launch_bounds__(256) void gatherB_kernel(
    const u32* __restrict__ feat /* [N*64] */, const int* __restrict__ gidx,
    const int* __restrict__ off, const int* __restrict__ degi,
    u32* __restrict__ outbf) {
  const int n = (blockIdx.x << 2) + (threadIdx.x >> 6);
  const int lane = threadIdx.x & 63;
  const int o = off[n], d = degi[n];
  float ax = 0.f, ay = 0.f;
  for (int c0 = 0; c0 < d; c0 += 64) {
    const int m = min(64, d - c0);
    const int g = (lane < m) ? gidx[o + c0 + lane] : 0;
    int i = 0;
    for (; i + 4 <= m; i += 4) {
      int s0 = __shfl(g, i), s1 = __shfl(g, i + 1), s2 = __shfl(g, i + 2), s3 = __shfl(g, i + 3);
      u32 v0 = feat[(size_t)s0 * 64 + lane];
      u32 v1 = feat[(size_t)s1 * 64 + lane];
      u32 v2 = feat[(size_t)s2 * 64 + lane];
      u32 v3 = feat[(size_t)s3 * 64 + lane];
      ax += bf_lo(v0) + bf_lo(v1) + bf_lo(v2) + bf_lo(v3);
      ay += bf_hi(v0) + bf_hi(v1) + bf_hi(v2) + bf_hi(v3);
    }
    for (; i < m; ++i) {
      int s0 = __shfl(g, i);
      u32 v0 = feat[(size_t)s0 * 64 + lane];
      ax += bf_lo(v0); ay += bf_hi(v0);
    }
  }
  outbf[(size_t)n * 64 + lane] = pack2(ax, ay);
}

// -------- pass C: hB[n] = rdeg[n] * sum_e LR(0.5*(Z[src]+Z[n]) + b); Z bf16 [N*128] --------
__global__ __launch_bounds__(256) void passC_kernel(
    const u32* __restrict__ Z, const int* __restrict__ esrc,
    const int* __restrict__ off, const int* __restrict__ degi,
    const float* __restrict__ rdeg, const float* __restrict__ bias,
    u32* __restrict__ hB) {
  const int n = (blockIdx.x << 2) + (threadIdx.x >> 6);
  const int lane = threadIdx.x & 63;
  const int o = off[n], d = degi[n];
  const uint2 znv = *(const uint2*)&Z[(size_t)n * 128 + (lane << 1)];
  const float4 zn = make_float4(bf_lo(znv.x), bf_hi(znv.x), bf_lo(znv.y), bf_hi(znv.y));
  const float4 bb = *(const float4*)&bias[lane << 2];
  float4 acc = make_float4(0.f, 0.f, 0.f, 0.f);
  for (int c0 = 0; c0 < d; c0 += 64) {
    const int m = min(64, d - c0);
    const int g = (lane < m) ? esrc[o + c0 + lane] : 0;
    int i = 0;
    for (; i + 2 <= m; i += 2) {
      int s0 = __shfl(g, i), s1 = __shfl(g, i + 1);
      uint2 z0 = *(const uint2*)&Z[(size_t)s0 * 128 + (lane << 1)];
      uint2 z1 = *(const uint2*)&Z[(size_t)s1 * 128 + (lane << 1)];
      acc_bf(acc, z0, zn, bb);
      acc_bf(acc, z1, zn, bb);
    }
    for (; i < m; ++i) {
      int s0 = __shfl(g, i);
      uint2 z0 = *(const uint2*)&Z[(size_t)s0 * 128 + (lane << 1)];
      acc_bf(acc, z0, zn, bb);
    }
  }
  const float r = rdeg[n];
  uint2 outv;
  outv.x = pack2(acc.x * r, acc.y * r);
  outv.y = pack2(acc.z * r, acc.w * r);
  *(uint2*)&hB[(size_t)n * 128 + (lane << 1)] = outv;
}

// -------- gather 256-wide bf16: h2B[n] = segsum(hB[src]) --------
__global__ __launch_bounds__(256) void gatherC_kernel(
    const u32* __restrict__ feat /* [N*128] */, const int* __restrict__ gidx,
    const int* __restrict__ off, const int* __restrict__ degi,
    u32* __restrict__ outbf) {
  const int n = (blockIdx.x << 2) + (threadIdx.x >> 6);
  const int lane = threadIdx.x & 63;
  const int o = off[n], d = degi[n];
  float4 acc = make_float4(0.f, 0.f, 0.f, 0.f);
  for (int c0 = 0; c0 < d; c0 += 64) {
    const int m = min(64, d - c0);
    const int g = (lane < m) ? gidx[o + c0 + lane] : 0;
    int i = 0;
    for (; i + 2 <= m; i += 2) {
      int s0 = __shfl(g, i), s1 = __shfl(g, i + 1);
      uint2 z0 = *(const uint2*)&feat[(size_t)s0 * 128 + (lane << 1)];
      uint2 z1 = *(const uint2*)&feat[(size_t)s1 * 128 + (lane << 1)];
      acc.x += bf_lo(z0.x) + bf_lo(z1.x);
      acc.y += bf_hi(z0.x) + bf_hi(z1.x);
      acc.z += bf_lo(z0.y) + bf_lo(z1.y);
      acc.w += bf_hi(z0.y) + bf_hi(z1.y);
    }
    for (; i < m; ++i) {
      int s0 = __shfl(g, i);
      uint2 z0 = *(const uint2*)&feat[(size_t)s0 * 128 + (lane << 1)];
      acc.x += bf_lo(z0.x); acc.y += bf_hi(z0.x);
      acc.z += bf_lo(z0.y); acc.w += bf_hi(z0.y);
    }
  }
  uint2 outv;
  outv.x = pack2(acc.x, acc.y);
  outv.y = pack2(acc.z, acc.w);
  *(uint2*)&outbf[(size_t)n * 128 + (lane << 1)] = outv;
}

// -------- pass E: per-block partial sums of LR(0.5*(Z2[src]+Z2[n]) + b) over all edges --------
__global__ __launch_bounds__(256) void passE_kernel(
    const u32* __restrict__ Z2, const int* __restrict__ esrc,
    const int* __restrict__ off, const int* __restrict__ degi,
    const float* __restrict__ bias, float* __restrict__ partials, int nNodes) {
  const int lane = threadIdx.x & 63, w = threadIdx.x >> 6;
  const int gw = blockIdx.x * 4 + w, nw = gridDim.x * 4;
  const float4 bb = *(const float4*)&bias[lane << 2];
  float4 acc = make_float4(0.f, 0.f, 0.f, 0.f);
  for (int n = gw; n < nNodes; n += nw) {
    const int o = off[n], d = degi[n];
    const uint2 znv = *(const uint2*)&Z2[(size_t)n * 128 + (lane << 1)];
    const float4 zn = make_float4(bf_lo(znv.x), bf_hi(znv.x), bf_lo(znv.y), bf_hi(znv.y));
    for (int c0 = 0; c0 < d; c0 += 64) {
      const int m = min(64, d - c0);
      const int g = (lane < m) ? esrc[o + c0 + lane] : 0;
      int i = 0;
      for (; i + 2 <= m; i += 2) {
        int s0 = __shfl(g, i), s1 = __shfl(g, i + 1);
        uint2 z0 = *(const uint2*)&Z2[(size_t)s0 * 128 + (lane << 1)];
        uint2 z1 = *(const uint2*)&Z2[(size_t)s1 * 128 + (lane << 1)];
        acc_bf(acc, z0, zn, bb);
        acc_bf(acc, z1, zn, bb);
      }
      for (; i < m; ++i) {
        int s0 = __shfl(g, i);
        uint2 z0 = *(const uint2*)&Z2[(size_t)s0 * 128 + (lane << 1)];
        acc_bf(acc, z0, zn, bb);
      }
    }
  }
  __shared__ float red[4][256];
  *(float4*)&red[w][lane << 2] = acc;
  __syncthreads();
  if (w == 0) {
    float4 s0 = *(const float4*)&red[0][lane << 2];
    float4 s1 = *(const float4*)&red[1][lane << 2];
    float4 s2 = *(const float4*)&red[2][lane << 2];
    float4 s3 = *(const float4*)&red[3][lane << 2];
    float4 s = make_float4(s0.x + s1.x + s2.x + s3.x, s0.y + s1.y + s2.y + s3.y,
                           s0.z + s1.z + s2.z + s3.z, s0.w + s1.w + s2.w + s3.w);
    *(float4*)&partials[(size_t)blockIdx.x * 256 + (lane << 2)] = s;
  }
}

__global__ __launch_bounds__(256) void reduce_partials_kernel(const float* __restrict__ partials,
                                                              int nparts, float* __restrict__ macc) {
  const int f = threadIdx.x;  // 256
  float s = 0.f;
  for (int b = 0; b < nparts; ++b) s += partials[(size_t)b * 256 + f];
  macc[f] = s;
}

// -------- GEMM: C[n][o] = sum_k A[n][k] * W[o][k]; A bf16 [N][K], W f32, C bf16; O=256 --------
template <int K>
__global__ __launch_bounds__(256) void gemm_bf_kernel(const u32* __restrict__ A /* [N][K/2] */,
                                                      const float* __restrict__ W,
                                                      u32* __restrict__ Cbf /* [N][128] */, int N) {
  __shared__ float As[16][68];
  __shared__ float Ws[16][68];
  const int bn = blockIdx.x * 64;
  const int bo = blockIdx.y * 64;
  const int tid = threadIdx.x;
  const int ln = tid >> 2;         // 0..63 load row
  const int lk = (tid & 3) << 2;   // 0,4,8,12 load k
  const int tn = (tid & 15) << 2;  // micro-tile node
  const int to = (tid >> 4) << 2;  // micro-tile out
  float acc[4][4] = {};
  for (int k0 = 0; k0 < K; k0 += 16) {
    uint2 av = make_uint2(0u, 0u);
    if (bn + ln < N) av = *(const uint2*)&A[(size_t)(bn + ln) * (K / 2) + ((k0 + lk) >> 1)];
    const float4 wl = *(const float4*)&W[(size_t)(bo + ln) * K + k0 + lk];
    As[lk + 0][ln] = bf_lo(av.x); As[lk + 1][ln] = bf_hi(av.x);
    As[lk + 2][ln] = bf_lo(av.y); As[lk + 3][ln] = bf_hi(av.y);
    Ws[lk + 0][ln] = wl.x; Ws[lk + 1][ln] = wl.y; Ws[lk + 2][ln] = wl.z; Ws[lk + 3][ln] = wl.w;
    __syncthreads();
#pragma unroll
    for (int kk = 0; kk < 16; ++kk) {
      float4 av4 = *(const float4*)&As[kk][tn];
      float4 wv4 = *(const float4*)&Ws[kk][to];
      float aarr[4] = {av4.x, av4.y, av4.z, av4.w};
      float warr[4] = {wv4.x, wv4.y, wv4.z, wv4.w};
#pragma unroll
      for (int i = 0; i < 4; ++i)
#pragma unroll
        for (int j = 0; j < 4; ++j) acc[i][j] = fmaf(aarr[i], warr[j], acc[i][j]);
    }
    __syncthreads();
  }
#pragma unroll
  for (int i = 0; i < 4; ++i) {
    const int n = bn + tn + i;
    if (n < NN) {
      uint2 outv;
      outv.x = pack2(acc[i][0], acc[i][1]);
      outv.y = pack2(acc[i][2], acc[i][3]);
      *(uint2*)&Cbf[(size_t)n * 128 + ((bo + to) >> 1)] = outv;
    }
  }
}

// -------- final: out[j] = b3[j] + invE * sum_k macc[k] * W3[j][k] --------
__global__ __launch_bounds__(256) void final_kernel(const float* __restrict__ macc1,
                                                    const float* __restrict__ macc2,
                                                    const float* __restrict__ W3,
                                                    const float* __restrict__ b3,
                                                    float* __restrict__ out, float invE) {
  __shared__ float red[4][64];
  const int j = threadIdx.x & 63, part = threadIdx.x >> 6;
  float acc = 0.f;
  for (int kk = 0; kk < 128; ++kk) {
    const int k = part * 128 + kk;
    const float mv = (k < 256) ? macc1[k] : macc2[k - 256];
    acc += mv * W3[(size_t)j * 512 + k];
  }
  red[part][j] = acc;
  __syncthreads();
  if (part == 0)
    out[j] = b3[j] + (red[0][j] + red[1][j] + red[2][j] + red[3][j]) * invE;
}

extern "C" void kernel_launch(void* const* d_in, const int* in_sizes, int n_in,
                              void* d_out, int out_size, void* d_ws, size_t ws_size,
                              hipStream_t stream) {
  const float* in1 = (const float*)d_in[0];
  const int* src1 = (const int*)d_in[1];
  const int* dst1 = (const int*)d_in[2];
  const float* in2 = (const float*)d_in[3];
  const int* src2 = (const int*)d_in[4];
  const int* dst2 = (const int*)d_in[5];
  const float* W11 = (const float*)d_in[6];
  const float* b11 = (const float*)d_in[7];
  const float* W12 = (const float*)d_in[8];
  const float* b12 = (const float*)d_in[9];
  const float* W21 = (const float*)d_in[10];
  const float* b21 = (const float*)d_in[11];
  const float* W22 = (const float*)d_in[12];
  const float* b22 = (const float*)d_in[13];
  const float* W3 = (const float*)d_in[14];
  const float* b3 = (const float*)d_in[15];
  const int E = in_sizes[1];
  const int N = NN;

  // ---- workspace carve (512B aligned) ----
  char* base = (char*)d_ws;
  size_t pos = 0;
  auto carve = [&](size_t bytes) -> char* {
    char* p = base + pos;
    pos = (pos + bytes + 511) & ~(size_t)511;
    return p;
  };
  int* degcur = (int*)carve((size_t)2 * N * sizeof(int));  // [deg | cursor]
  int* degi = degcur;
  int* cursor = degcur + N;
  int* off = (int*)carve((size_t)N * sizeof(int));
  float* rdeg = (float*)carve((size_t)N * sizeof(float));
  int* eid_s = (int*)carve((size_t)E * sizeof(int));
  int* esrc_s = (int*)carve((size_t)E * sizeof(int));
  u32* Hb = (u32*)carve((size_t)N * 64 * sizeof(u32));     // h   (bf16, 128 feats)
  u32* H2b = (u32*)carve((size_t)N * 64 * sizeof(u32));    // h2  (bf16, 128 feats)
  u32* Zb = (u32*)carve((size_t)N * 128 * sizeof(u32));    // Z / Z2 (bf16, 256 feats)
  u32* HBb = (u32*)carve((size_t)N * 128 * sizeof(u32));   // hB  (bf16, 256 feats)
  u32* H2Bb = (u32*)carve((size_t)N * 128 * sizeof(u32));  // h2B (bf16, 256 feats)
  float* partials = (float*)carve((size_t)256 * 256 * sizeof(float));
  float* macc1 = (float*)carve(256 * sizeof(float));
  float* macc2 = (float*)carve(256 * sizeof(float));
  (void)ws_size; (void)n_in; (void)out_size;

  const int EB = (E + 255) / 256;  // edge-parallel blocks
  const int NB = N / 4;            // wave-per-node blocks (4 waves/block)
  const dim3 gemm_grid((N + 63) / 64, 4);

  for (int g = 0; g < 2; ++g) {
    const float* inp = g ? in2 : in1;
    const int* src = g ? src2 : src1;
    const int* dst = g ? dst2 : dst1;
    const float* Wa = g ? W21 : W11;
    const float* ba = g ? b21 : b11;
    const float* Wb = g ? W22 : W12;
    const float* bb = g ? b22 : b12;
    float* macc = g ? macc2 : macc1;

    hipMemsetAsync(degcur, 0, (size_t)2 * N * sizeof(int), stream);
    count_kernel<<<EB, 256, 0, stream>>>(dst, degi, E);
    scan_rdeg_kernel<<<1, 1024, 0, stream>>>(degi, off, rdeg, N);
    fill_kernel<<<EB, 256, 0, stream>>>(src, dst, off, cursor, eid_s, esrc_s, E);

    // layer 1: h = segsum(inputs, dst)/deg ; h2 = segsum(h[src], dst) ; Z = h2 @ Wa.T
    gatherA_kernel<<<NB, 256, 0, stream>>>(inp, eid_s, off, degi, rdeg, Hb);
    gatherB_kernel<<<NB, 256, 0, stream>>>(Hb, esrc_s, off, degi, H2b);
    gemm_bf_kernel<128><<<gemm_grid, 256, 0, stream>>>(H2b, Wa, Zb, N);

    // layer 2 input: hB = rdeg * segsum(LR(0.5*(Z[src]+Z[dst])+ba), dst)
    passC_kernel<<<NB, 256, 0, stream>>>(Zb, esrc_s, off, degi, rdeg, ba, HBb);
    // h2B = segsum(hB[src], dst) ; Z2 = h2B @ Wb.T
    gatherC_kernel<<<NB, 256, 0, stream>>>(HBb, esrc_s, off, degi, H2Bb);
    gemm_bf_kernel<256><<<gemm_grid, 256, 0, stream>>>(H2Bb, Wb, Zb, N);

    // mean over edges of LR(0.5*(Z2[src]+Z2[dst])+bb)  (unscaled sum -> macc)
    passE_kernel<<<256, 256, 0, stream>>>(Zb, esrc_s, off, degi, bb, partials, N);
    reduce_partials_kernel<<<1, 256, 0, stream>>>(partials, 256, macc);
  }

  final_kernel<<<1, 256, 0, stream>>>(macc1, macc2, W3, b3, (float*)d_out, 1.0f / (float)E);
}

// Round 3
// 635.741 us; speedup vs baseline: 1.2335x; 1.0496x over previous
//
#include <hip/hip_runtime.h>
#include <cstddef>

#define NN 10000  // N_NODES

typedef unsigned int u32;
typedef unsigned short u16;
typedef __attribute__((ext_vector_type(8))) short short8;
typedef __attribute__((ext_vector_type(4))) float f32x4;

__device__ __forceinline__ float lrelu(float x) { return x >= 0.f ? x : 0.01f * x; }

// ---- bf16 helpers (tables stored bf16, math in f32) ----
__device__ __forceinline__ float bf_lo(u32 v) { union { u32 i; float f; } c; c.i = v << 16; return c.f; }
__device__ __forceinline__ float bf_hi(u32 v) { union { u32 i; float f; } c; c.i = v & 0xFFFF0000u; return c.f; }
__device__ __forceinline__ u32 rne_bits(float f) {
  union { float f; u32 i; } c; c.f = f;
  return c.i + 0x7FFFu + ((c.i >> 16) & 1u);
}
__device__ __forceinline__ u32 pack2(float a, float b) {
  return (rne_bits(a) >> 16) | (rne_bits(b) & 0xFFFF0000u);
}

// ---------------- weight convert: 4 matrices f32 -> bf16 ----------------
__global__ __launch_bounds__(256) void wconv_kernel(
    const float* __restrict__ a, const float* __restrict__ b,
    const float* __restrict__ c, const float* __restrict__ d,
    u16* __restrict__ oa, u16* __restrict__ ob,
    u16* __restrict__ oc, u16* __restrict__ od) {
  int i = blockIdx.x * 256 + threadIdx.x;  // grid covers 196608
  if (i < 32768) oa[i] = (u16)(rne_bits(a[i]) >> 16);
  else if (i < 98304) ob[i - 32768] = (u16)(rne_bits(b[i - 32768]) >> 16);
  else if (i < 131072) oc[i - 98304] = (u16)(rne_bits(c[i - 98304]) >> 16);
  else if (i < 196608) od[i - 131072] = (u16)(rne_bits(d[i - 131072]) >> 16);
}

// ---------------- CSR build ----------------
__global__ __launch_bounds__(256) void count_kernel(const int* __restrict__ dst,
                                                    int* __restrict__ degi, int E) {
  int e = blockIdx.x * 256 + threadIdx.x;
  if (e < E) atomicAdd(&degi[dst[e]], 1);
}

__global__ __launch_bounds__(1024) void scan_rdeg_kernel(const int* __restrict__ degi,
                                                         int* __restrict__ off,
                                                         float* __restrict__ rdeg, int n) {
  __shared__ int wsum[16];
  __shared__ int wpre[16];
  __shared__ int carry_s;
  const int tid = threadIdx.x;
  const int lane = tid & 63, w = tid >> 6;
  if (tid == 0) carry_s = 0;
  __syncthreads();
  for (int base = 0; base < n; base += 1024) {
    int i = base + tid;
    int x = (i < n) ? degi[i] : 0;
    int v = x;
#pragma unroll
    for (int d = 1; d < 64; d <<= 1) {
      int t = __shfl_up(v, d);
      if (lane >= d) v += t;
    }
    if (lane == 63) wsum[w] = v;
    __syncthreads();
    if (tid == 0) {
      int s = carry_s;
#pragma unroll
      for (int j = 0; j < 16; ++j) { int t = wsum[j]; wpre[j] = s; s += t; }
      carry_s = s;
    }
    __syncthreads();
    if (i < n) {
      off[i] = wpre[w] + (v - x);              // exclusive prefix
      rdeg[i] = 1.0f / fmaxf((float)x, 1.0f);  // 1/max(deg,1)
    }
    __syncthreads();
  }
}

__global__ __launch_bounds__(256) void fill_kernel(const int* __restrict__ src,
                                                   const int* __restrict__ dst,
                                                   const int* __restrict__ off,
                                                   int* __restrict__ cursor,
                                                   int* __restrict__ eid_s,
                                                   int* __restrict__ esrc_s, int E) {
  int e = blockIdx.x * 256 + threadIdx.x;
  if (e < E) {
    int d = dst[e];
    int p = off[d] + atomicAdd(&cursor[d], 1);
    eid_s[p] = e;
    esrc_s[p] = src[e];
  }
}

// -------- pass A: h[n] = rdeg * segsum(inputs[eid], dst); f32 in -> bf16 out (128 feats) --------
// half-wave scheme: 32 lanes x float4 = full 512B row; halves process alternate edges.
__global__ __launch_bounds__(256) void gatherA_kernel(
    const float* __restrict__ feat, const int* __restrict__ gidx,
    const int* __restrict__ off, const int* __restrict__ degi,
    const float* __restrict__ rdeg, u32* __restrict__ outbf /* [N*64] */) {
  const int n = (blockIdx.x << 2) + (threadIdx.x >> 6);
  const int lane = threadIdx.x & 63;
  const int hl = lane & 31, h = lane >> 5;
  const int o = off[n], d = degi[n];
  float4 acc = make_float4(0.f, 0.f, 0.f, 0.f);
  for (int c0 = 0; c0 < d; c0 += 64) {
    const int m = min(64, d - c0);
    const int g = (lane < m) ? gidx[o + c0 + lane] : 0;
    const int pairs = (m + 1) >> 1;
#pragma unroll 2
    for (int i = 0; i < pairs; ++i) {
      const int e = 2 * i + h;
      const int s = __shfl(g, e < m ? e : (m - 1));
      const float wgt = (e < m) ? 1.f : 0.f;
      const float4 v = *(const float4*)&feat[(size_t)s * 128 + (hl << 2)];
      acc.x = fmaf(v.x, wgt, acc.x);
      acc.y = fmaf(v.y, wgt, acc.y);
      acc.z = fmaf(v.z, wgt, acc.z);
      acc.w = fmaf(v.w, wgt, acc.w);
    }
  }
  acc.x += __shfl(acc.x, lane ^ 32);
  acc.y += __shfl(acc.y, lane ^ 32);
  acc.z += __shfl(acc.z, lane ^ 32);
  acc.w += __shfl(acc.w, lane ^ 32);
  if (h == 0) {
    const float sc = rdeg[n];
    uint2 r;
    r.x = pack2(acc.x * sc, acc.y * sc);
    r.y = pack2(acc.z * sc, acc.w * sc);
    *(uint2*)&outbf[(size_t)n * 64 + (hl << 1)] = r;
  }
}

// -------- pass B: h2[n] = segsum(h[src]); bf16 table (128 feats, 256B rows) --------
__global__ __launch_bounds__(256) void gatherB_kernel(
    const u32* __restrict__ feat /* [N*64] */, const int* __restrict__ gidx,
    const int* __restrict__ off, const int* __restrict__ degi,
    u32* __restrict__ outbf) {
  const int n = (blockIdx.x << 2) + (threadIdx.x >> 6);
  const int lane = threadIdx.x & 63;
  const int hl = lane & 31, h = lane >> 5;
  const int o = off[n], d = degi[n];
  float4 acc = make_float4(0.f, 0.f, 0.f, 0.f);
  for (int c0 = 0; c0 < d; c0 += 64) {
    const int m = min(64, d - c0);
    const int g = (lane < m) ? gidx[o + c0 + lane] : 0;
    const int pairs = (m + 1) >> 1;
#pragma unroll 2
    for (int i = 0; i < pairs; ++i) {
      const int e = 2 * i + h;
      const int s = __shfl(g, e < m ? e : (m - 1));
      const float wgt = (e < m) ? 1.f : 0.f;
      const uint2 v = *(const uint2*)&feat[(size_t)s * 64 + (hl << 1)];
      acc.x = fmaf(bf_lo(v.x), wgt, acc.x);
      acc.y = fmaf(bf_hi(v.x), wgt, acc.y);
      acc.z = fmaf(bf_lo(v.y), wgt, acc.z);
      acc.w = fmaf(bf_hi(v.y), wgt, acc.w);
    }
  }
  acc.x += __shfl(acc.x, lane ^ 32);
  acc.y += __shfl(acc.y, lane ^ 32);
  acc.z += __shfl(acc.z, lane ^ 32);
  acc.w += __shfl(acc.w, lane ^ 32);
  if (h == 0) {
    uint2 r;
    r.x = pack2(acc.x, acc.y);
    r.y = pack2(acc.z, acc.w);
    *(uint2*)&outbf[(size_t)n * 64 + (hl << 1)] = r;
  }
}

// ---- 8-feat edge accumulate for 256-wide passes ----
__device__ __forceinline__ void acc_bf8(float4& aL, float4& aH, uint4 v,
                                        const float4& znL, const float4& znH,
                                        const float4& bL, const float4& bH, float wgt) {
  aL.x += wgt * lrelu(0.5f * (bf_lo(v.x) + znL.x) + bL.x);
  aL.y += wgt * lrelu(0.5f * (bf_hi(v.x) + znL.y) + bL.y);
  aL.z += wgt * lrelu(0.5f * (bf_lo(v.y) + znL.z) + bL.z);
  aL.w += wgt * lrelu(0.5f * (bf_hi(v.y) + znL.w) + bL.w);
  aH.x += wgt * lrelu(0.5f * (bf_lo(v.z) + znH.x) + bH.x);
  aH.y += wgt * lrelu(0.5f * (bf_hi(v.z) + znH.y) + bH.y);
  aH.z += wgt * lrelu(0.5f * (bf_lo(v.w) + znH.z) + bH.z);
  aH.w += wgt * lrelu(0.5f * (bf_hi(v.w) + znH.w) + bH.w);
}

// -------- pass C: hB[n] = rdeg[n] * sum_e LR(0.5*(Z[src]+Z[n]) + b); Z bf16 [N][256] --------
__global__ __launch_bounds__(256) void passC_kernel(
    const u32* __restrict__ Z, const int* __restrict__ esrc,
    const int* __restrict__ off, const int* __restrict__ degi,
    const float* __restrict__ rdeg, const float* __restrict__ bias,
    u32* __restrict__ hB) {
  const int n = (blockIdx.x << 2) + (threadIdx.x >> 6);
  const int lane = threadIdx.x & 63;
  const int hl = lane & 31, h = lane >> 5;
  const int o = off[n], d = degi[n];
  const uint4 znv = *(const uint4*)&Z[(size_t)n * 128 + (hl << 2)];
  const float4 znL = make_float4(bf_lo(znv.x), bf_hi(znv.x), bf_lo(znv.y), bf_hi(znv.y));
  const float4 znH = make_float4(bf_lo(znv.z), bf_hi(znv.z), bf_lo(znv.w), bf_hi(znv.w));
  const float4 bL = *(const float4*)&bias[hl << 3];
  const float4 bH = *(const float4*)&bias[(hl << 3) + 4];
  float4 aL = make_float4(0.f, 0.f, 0.f, 0.f), aH = make_float4(0.f, 0.f, 0.f, 0.f);
  for (int c0 = 0; c0 < d; c0 += 64) {
    const int m = min(64, d - c0);
    const int g = (lane < m) ? esrc[o + c0 + lane] : 0;
    const int pairs = (m + 1) >> 1;
#pragma unroll 2
    for (int i = 0; i < pairs; ++i) {
      const int e = 2 * i + h;
      const int s = __shfl(g, e < m ? e : (m - 1));
      const float wgt = (e < m) ? 1.f : 0.f;
      const uint4 z = *(const uint4*)&Z[(size_t)s * 128 + (hl << 2)];
      acc_bf8(aL, aH, z, znL, znH, bL, bH, wgt);
    }
  }
  aL.x += __shfl(aL.x, lane ^ 32); aL.y += __shfl(aL.y, lane ^ 32);
  aL.z += __shfl(aL.z, lane ^ 32); aL.w += __shfl(aL.w, lane ^ 32);
  aH.x += __shfl(aH.x, lane ^ 32); aH.y += __shfl(aH.y, lane ^ 32);
  aH.z += __shfl(aH.z, lane ^ 32); aH.w += __shfl(aH.w, lane ^ 32);
  if (h == 0) {
    const float r = rdeg[n];
    uint4 outv;
    outv.x = pack2(aL.x * r, aL.y * r);
    outv.y = pack2(aL.z * r, aL.w * r);
    outv.z = pack2(aH.x * r, aH.y * r);
    outv.w = pack2(aH.z * r, aH.w * r);
    *(uint4*)&hB[(size_t)n * 128 + (hl << 2)] = outv;
  }
}

// -------- gather 256-wide bf16: h2B[n] = segsum(hB[src]) --------
__global__ __launch_bounds__(256) void gatherC_kernel(
    const u32* __restrict__ feat /* [N*128] */, const int* __restrict__ gidx,
    const int* __restrict__ off, const int* __restrict__ degi,
    u32* __restrict__ outbf) {
  const int n = (blockIdx.x << 2) + (threadIdx.x >> 6);
  const int lane = threadIdx.x & 63;
  const int hl = lane & 31, h = lane >> 5;
  const int o = off[n], d = degi[n];
  float4 aL = make_float4(0.f, 0.f, 0.f, 0.f), aH = make_float4(0.f, 0.f, 0.f, 0.f);
  for (int c0 = 0; c0 < d; c0 += 64) {
    const int m = min(64, d - c0);
    const int g = (lane < m) ? gidx[o + c0 + lane] : 0;
    const int pairs = (m + 1) >> 1;
#pragma unroll 2
    for (int i = 0; i < pairs; ++i) {
      const int e = 2 * i + h;
      const int s = __shfl(g, e < m ? e : (m - 1));
      const float wgt = (e < m) ? 1.f : 0.f;
      const uint4 z = *(const uint4*)&feat[(size_t)s * 128 + (hl << 2)];
      aL.x = fmaf(bf_lo(z.x), wgt, aL.x);
      aL.y = fmaf(bf_hi(z.x), wgt, aL.y);
      aL.z = fmaf(bf_lo(z.y), wgt, aL.z);
      aL.w = fmaf(bf_hi(z.y), wgt, aL.w);
      aH.x = fmaf(bf_lo(z.z), wgt, aH.x);
      aH.y = fmaf(bf_hi(z.z), wgt, aH.y);
      aH.z = fmaf(bf_lo(z.w), wgt, aH.z);
      aH.w = fmaf(bf_hi(z.w), wgt, aH.w);
    }
  }
  aL.x += __shfl(aL.x, lane ^ 32); aL.y += __shfl(aL.y, lane ^ 32);
  aL.z += __shfl(aL.z, lane ^ 32); aL.w += __shfl(aL.w, lane ^ 32);
  aH.x += __shfl(aH.x, lane ^ 32); aH.y += __shfl(aH.y, lane ^ 32);
  aH.z += __shfl(aH.z, lane ^ 32); aH.w += __shfl(aH.w, lane ^ 32);
  if (h == 0) {
    uint4 outv;
    outv.x = pack2(aL.x, aL.y);
    outv.y = pack2(aL.z, aL.w);
    outv.z = pack2(aH.x, aH.y);
    outv.w = pack2(aH.z, aH.w);
    *(uint4*)&outbf[(size_t)n * 128 + (hl << 2)] = outv;
  }
}

// -------- pass E: per-block partial sums of LR(0.5*(Z2[src]+Z2[n]) + b) over all edges --------
__global__ __launch_bounds__(256) void passE_kernel(
    const u32* __restrict__ Z2, const int* __restrict__ esrc,
    const int* __restrict__ off, const int* __restrict__ degi,
    const float* __restrict__ bias, float* __restrict__ partials, int nNodes) {
  const int lane = threadIdx.x & 63, w = threadIdx.x >> 6;
  const int hl = lane & 31, h = lane >> 5;
  const int gw = blockIdx.x * 4 + w, nw = gridDim.x * 4;
  const float4 bL = *(const float4*)&bias[hl << 3];
  const float4 bH = *(const float4*)&bias[(hl << 3) + 4];
  float4 aL = make_float4(0.f, 0.f, 0.f, 0.f), aH = make_float4(0.f, 0.f, 0.f, 0.f);
  for (int n = gw; n < nNodes; n += nw) {
    const int o = off[n], d = degi[n];
    const uint4 znv = *(const uint4*)&Z2[(size_t)n * 128 + (hl << 2)];
    const float4 znL = make_float4(bf_lo(znv.x), bf_hi(znv.x), bf_lo(znv.y), bf_hi(znv.y));
    const float4 znH = make_float4(bf_lo(znv.z), bf_hi(znv.z), bf_lo(znv.w), bf_hi(znv.w));
    for (int c0 = 0; c0 < d; c0 += 64) {
      const int m = min(64, d - c0);
      const int g = (lane < m) ? esrc[o + c0 + lane] : 0;
      const int pairs = (m + 1) >> 1;
#pragma unroll 2
      for (int i = 0; i < pairs; ++i) {
        const int e = 2 * i + h;
        const int s = __shfl(g, e < m ? e : (m - 1));
        const float wgt = (e < m) ? 1.f : 0.f;
        const uint4 z = *(const uint4*)&Z2[(size_t)s * 128 + (hl << 2)];
        acc_bf8(aL, aH, z, znL, znH, bL, bH, wgt);
      }
    }
  }
  aL.x += __shfl(aL.x, lane ^ 32); aL.y += __shfl(aL.y, lane ^ 32);
  aL.z += __shfl(aL.z, lane ^ 32); aL.w += __shfl(aL.w, lane ^ 32);
  aH.x += __shfl(aH.x, lane ^ 32); aH.y += __shfl(aH.y, lane ^ 32);
  aH.z += __shfl(aH.z, lane ^ 32); aH.w += __shfl(aH.w, lane ^ 32);
  __shared__ float red[4][256];
  if (h == 0) {
    *(float4*)&red[w][hl << 3] = aL;
    *(float4*)&red[w][(hl << 3) + 4] = aH;
  }
  __syncthreads();
  if (w == 0) {
    float4 s0 = *(const float4*)&red[0][lane << 2];
    float4 s1 = *(const float4*)&red[1][lane << 2];
    float4 s2 = *(const float4*)&red[2][lane << 2];
    float4 s3 = *(const float4*)&red[3][lane << 2];
    float4 s = make_float4(s0.x + s1.x + s2.x + s3.x, s0.y + s1.y + s2.y + s3.y,
                           s0.z + s1.z + s2.z + s3.z, s0.w + s1.w + s2.w + s3.w);
    *(float4*)&partials[(size_t)blockIdx.x * 256 + (lane << 2)] = s;
  }
}

__global__ __launch_bounds__(256) void reduce_partials_kernel(const float* __restrict__ partials,
                                                              int nparts, float* __restrict__ macc) {
  const int f = threadIdx.x;  // 256
  float s = 0.f;
  for (int b = 0; b < nparts; ++b) s += partials[(size_t)b * 256 + f];
  macc[f] = s;
}

// -------- MFMA GEMM: C[n][o] = sum_k A[n][k]*W[o][k]; A,W,C bf16; O=256 --------
// block = 4 waves (2x2), block tile 64x64; wave tile 32x32 (2x2 frags of 16x16x32).
template <int K>
__global__ __launch_bounds__(256) void gemm_mfma_kernel(const u16* __restrict__ A,
                                                        const u16* __restrict__ Wb,
                                                        u16* __restrict__ C, int N) {
  const int lane = threadIdx.x & 63;
  const int w = threadIdx.x >> 6;
  const int wm = w >> 1, wn = w & 1;
  const int bn = blockIdx.x * 64 + wm * 32;
  const int bo = blockIdx.y * 64 + wn * 32;
  const int r0 = lane & 15;   // A-row / B-col within 16-tile
  const int kq = lane >> 4;   // k-quarter: 8 elems each
  const int ra0 = min(bn + r0, N - 1);
  const int ra1 = min(bn + 16 + r0, N - 1);
  const u16* a0p = &A[(size_t)ra0 * K + kq * 8];
  const u16* a1p = &A[(size_t)ra1 * K + kq * 8];
  const u16* b0p = &Wb[(size_t)(bo + r0) * K + kq * 8];
  const u16* b1p = &Wb[(size_t)(bo + 16 + r0) * K + kq * 8];
  f32x4 acc00 = {0.f, 0.f, 0.f, 0.f}, acc01 = {0.f, 0.f, 0.f, 0.f};
  f32x4 acc10 = {0.f, 0.f, 0.f, 0.f}, acc11 = {0.f, 0.f, 0.f, 0.f};
#pragma unroll
  for (int k0 = 0; k0 < K; k0 += 32) {
    const short8 a0 = *(const short8*)(a0p + k0);
    const short8 a1 = *(const short8*)(a1p + k0);
    const short8 b0 = *(const short8*)(b0p + k0);
    const short8 b1 = *(const short8*)(b1p + k0);
    acc00 = __builtin_amdgcn_mfma_f32_16x16x32_bf16(a0, b0, acc00, 0, 0, 0);
    acc01 = __builtin_amdgcn_mfma_f32_16x16x32_bf16(a0, b1, acc01, 0, 0, 0);
    acc10 = __builtin_amdgcn_mfma_f32_16x16x32_bf16(a1, b0, acc10, 0, 0, 0);
    acc11 = __builtin_amdgcn_mfma_f32_16x16x32_bf16(a1, b1, acc11, 0, 0, 0);
  }
  // D layout: row = 4*kq + r (within 16-tile), col = r0
#pragma unroll
  for (int r = 0; r < 4; ++r) {
    const int n0 = bn + 4 * kq + r;
    if (n0 < N) {
      C[(size_t)n0 * 256 + bo + r0] = (u16)(rne_bits(acc00[r]) >> 16);
      C[(size_t)n0 * 256 + bo + 16 + r0] = (u16)(rne_bits(acc01[r]) >> 16);
    }
    const int n1 = bn + 16 + 4 * kq + r;
    if (n1 < N) {
      C[(size_t)n1 * 256 + bo + r0] = (u16)(rne_bits(acc10[r]) >> 16);
      C[(size_t)n1 * 256 + bo + 16 + r0] = (u16)(rne_bits(acc11[r]) >> 16);
    }
  }
}

// -------- final: out[j] = b3[j] + invE * sum_k macc[k] * W3[j][k] --------
__global__ __launch_bounds__(256) void final_kernel(const float* __restrict__ macc1,
                                                    const float* __restrict__ macc2,
                                                    const float* __restrict__ W3,
                                                    const float* __restrict__ b3,
                                                    float* __restrict__ out, float invE) {
  __shared__ float red[4][64];
  const int j = threadIdx.x & 63, part = threadIdx.x >> 6;
  float acc = 0.f;
  for (int kk = 0; kk < 128; ++kk) {
    const int k = part * 128 + kk;
    const float mv = (k < 256) ? macc1[k] : macc2[k - 256];
    acc += mv * W3[(size_t)j * 512 + k];
  }
  red[part][j] = acc;
  __syncthreads();
  if (part == 0)
    out[j] = b3[j] + (red[0][j] + red[1][j] + red[2][j] + red[3][j]) * invE;
}

extern "C" void kernel_launch(void* const* d_in, const int* in_sizes, int n_in,
                              void* d_out, int out_size, void* d_ws, size_t ws_size,
                              hipStream_t stream) {
  const float* in1 = (const float*)d_in[0];
  const int* src1 = (const int*)d_in[1];
  const int* dst1 = (const int*)d_in[2];
  const float* in2 = (const float*)d_in[3];
  const int* src2 = (const int*)d_in[4];
  const int* dst2 = (const int*)d_in[5];
  const float* W11 = (const float*)d_in[6];
  const float* b11 = (const float*)d_in[7];
  const float* W12 = (const float*)d_in[8];
  const float* b12 = (const float*)d_in[9];
  const float* W21 = (const float*)d_in[10];
  const float* b21 = (const float*)d_in[11];
  const float* W22 = (const float*)d_in[12];
  const float* b22 = (const float*)d_in[13];
  const float* W3 = (const float*)d_in[14];
  const float* b3 = (const float*)d_in[15];
  const int E = in_sizes[1];
  const int N = NN;

  // ---- workspace carve (512B aligned) ----
  char* base = (char*)d_ws;
  size_t pos = 0;
  auto carve = [&](size_t bytes) -> char* {
    char* p = base + pos;
    pos = (pos + bytes + 511) & ~(size_t)511;
    return p;
  };
  int* degcur = (int*)carve((size_t)2 * N * sizeof(int));  // [deg | cursor]
  int* degi = degcur;
  int* cursor = degcur + N;
  int* off = (int*)carve((size_t)N * sizeof(int));
  float* rdeg = (float*)carve((size_t)N * sizeof(float));
  int* eid_s = (int*)carve((size_t)E * sizeof(int));
  int* esrc_s = (int*)carve((size_t)E * sizeof(int));
  u32* Hb = (u32*)carve((size_t)N * 64 * sizeof(u32));     // h   (bf16, 128 feats)
  u32* H2b = (u32*)carve((size_t)N * 64 * sizeof(u32));    // h2  (bf16, 128 feats)
  u32* Zb = (u32*)carve((size_t)N * 128 * sizeof(u32));    // Z / Z2 (bf16, 256 feats)
  u32* HBb = (u32*)carve((size_t)N * 128 * sizeof(u32));   // hB  (bf16, 256 feats)
  u32* H2Bb = (u32*)carve((size_t)N * 128 * sizeof(u32));  // h2B (bf16, 256 feats)
  u16* Wa1 = (u16*)carve((size_t)32768 * sizeof(u16));     // W11 bf16
  u16* Wb1 = (u16*)carve((size_t)65536 * sizeof(u16));     // W12 bf16
  u16* Wa2 = (u16*)carve((size_t)32768 * sizeof(u16));     // W21 bf16
  u16* Wb2 = (u16*)carve((size_t)65536 * sizeof(u16));     // W22 bf16
  float* partials = (float*)carve((size_t)256 * 256 * sizeof(float));
  float* macc1 = (float*)carve(256 * sizeof(float));
  float* macc2 = (float*)carve(256 * sizeof(float));
  (void)ws_size; (void)n_in; (void)out_size;

  const int EB = (E + 255) / 256;  // edge-parallel blocks
  const int NB = N / 4;            // wave-per-node blocks (4 waves/block)
  const dim3 gemm_grid((N + 63) / 64, 4);

  wconv_kernel<<<768, 256, 0, stream>>>(W11, W12, W21, W22, Wa1, Wb1, Wa2, Wb2);

  for (int g = 0; g < 2; ++g) {
    const float* inp = g ? in2 : in1;
    const int* src = g ? src2 : src1;
    const int* dst = g ? dst2 : dst1;
    const u16* Wa = g ? Wa2 : Wa1;
    const float* ba = g ? b21 : b11;
    const u16* Wb = g ? Wb2 : Wb1;
    const float* bb = g ? b22 : b12;
    float* macc = g ? macc2 : macc1;

    hipMemsetAsync(degcur, 0, (size_t)2 * N * sizeof(int), stream);
    count_kernel<<<EB, 256, 0, stream>>>(dst, degi, E);
    scan_rdeg_kernel<<<1, 1024, 0, stream>>>(degi, off, rdeg, N);
    fill_kernel<<<EB, 256, 0, stream>>>(src, dst, off, cursor, eid_s, esrc_s, E);

    // layer 1: h = segsum(inputs, dst)/deg ; h2 = segsum(h[src], dst) ; Z = h2 @ Wa.T
    gatherA_kernel<<<NB, 256, 0, stream>>>(inp, eid_s, off, degi, rdeg, Hb);
    gatherB_kernel<<<NB, 256, 0, stream>>>(Hb, esrc_s, off, degi, H2b);
    gemm_mfma_kernel<128><<<gemm_grid, 256, 0, stream>>>((const u16*)H2b, Wa, (u16*)Zb, N);

    // layer 2 input: hB = rdeg * segsum(LR(0.5*(Z[src]+Z[dst])+ba), dst)
    passC_kernel<<<NB, 256, 0, stream>>>(Zb, esrc_s, off, degi, rdeg, ba, HBb);
    // h2B = segsum(hB[src], dst) ; Z2 = h2B @ Wb.T
    gatherC_kernel<<<NB, 256, 0, stream>>>(HBb, esrc_s, off, degi, H2Bb);
    gemm_mfma_kernel<256><<<gemm_grid, 256, 0, stream>>>((const u16*)H2Bb, Wb, (u16*)Zb, N);

    // mean over edges of LR(0.5*(Z2[src]+Z2[dst])+bb)  (unscaled sum -> macc)
    passE_kernel<<<256, 256, 0, stream>>>(Zb, esrc_s, off, degi, bb, partials, N);
    reduce_partials_kernel<<<1, 256, 0, stream>>>(partials, 256, macc);
  }

  final_kernel<<<1, 256, 0, stream>>>(macc1, macc2, W3, b3, (float*)d_out, 1.0f / (float)E);
}

// Round 4
// 417.133 us; speedup vs baseline: 1.8800x; 1.5241x over previous
//
#include <hip/hip_runtime.h>
#include <cstddef>

#define NN 10000  // N_NODES

typedef unsigned int u32;
typedef unsigned short u16;
typedef __attribute__((ext_vector_type(8))) short short8;
typedef __attribute__((ext_vector_type(4))) float f32x4;

__device__ __forceinline__ float lrelu(float x) { return x >= 0.f ? x : 0.01f * x; }

// ---- bf16 helpers (tables stored bf16, math in f32) ----
__device__ __forceinline__ float bf_lo(u32 v) { union { u32 i; float f; } c; c.i = v << 16; return c.f; }
__device__ __forceinline__ float bf_hi(u32 v) { union { u32 i; float f; } c; c.i = v & 0xFFFF0000u; return c.f; }
__device__ __forceinline__ u32 rne_bits(float f) {
  union { float f; u32 i; } c; c.f = f;
  return c.i + 0x7FFFu + ((c.i >> 16) & 1u);
}
__device__ __forceinline__ u32 pack2(float a, float b) {
  return (rne_bits(a) >> 16) | (rne_bits(b) & 0xFFFF0000u);
}

// ---------------- weight convert: 4 matrices f32 -> bf16 ----------------
__global__ __launch_bounds__(256) void wconv_kernel(
    const float* __restrict__ a, const float* __restrict__ b,
    const float* __restrict__ c, const float* __restrict__ d,
    u16* __restrict__ oa, u16* __restrict__ ob,
    u16* __restrict__ oc, u16* __restrict__ od) {
  int i = blockIdx.x * 256 + threadIdx.x;  // grid covers 196608
  if (i < 32768) oa[i] = (u16)(rne_bits(a[i]) >> 16);
  else if (i < 98304) ob[i - 32768] = (u16)(rne_bits(b[i - 32768]) >> 16);
  else if (i < 131072) oc[i - 98304] = (u16)(rne_bits(c[i - 98304]) >> 16);
  else if (i < 196608) od[i - 131072] = (u16)(rne_bits(d[i - 131072]) >> 16);
}

// ---------------- CSR build (batched over 2 graphs via blockIdx.y) ----------------
__global__ __launch_bounds__(256) void count_b_kernel(const int* __restrict__ dstA,
                                                      const int* __restrict__ dstB,
                                                      int* __restrict__ degbase, int E) {
  const int g = blockIdx.y;
  const int* dst = g ? dstB : dstA;
  int* degi = degbase + (size_t)g * 2 * NN;
  int e = blockIdx.x * 256 + threadIdx.x;
  if (e < E) atomicAdd(&degi[dst[e]], 1);
}

__global__ __launch_bounds__(1024) void scan_b_kernel(const int* __restrict__ degbase,
                                                      int* __restrict__ offbase,
                                                      float* __restrict__ rdegbase, int n) {
  const int g = blockIdx.x;
  const int* degi = degbase + (size_t)g * 2 * NN;
  int* off = offbase + (size_t)g * NN;
  float* rdeg = rdegbase + (size_t)g * NN;
  __shared__ int wsum[16];
  __shared__ int wpre[16];
  __shared__ int carry_s;
  const int tid = threadIdx.x;
  const int lane = tid & 63, w = tid >> 6;
  if (tid == 0) carry_s = 0;
  __syncthreads();
  for (int base = 0; base < n; base += 1024) {
    int i = base + tid;
    int x = (i < n) ? degi[i] : 0;
    int v = x;
#pragma unroll
    for (int d = 1; d < 64; d <<= 1) {
      int t = __shfl_up(v, d);
      if (lane >= d) v += t;
    }
    if (lane == 63) wsum[w] = v;
    __syncthreads();
    if (tid == 0) {
      int s = carry_s;
#pragma unroll
      for (int j = 0; j < 16; ++j) { int t = wsum[j]; wpre[j] = s; s += t; }
      carry_s = s;
    }
    __syncthreads();
    if (i < n) {
      off[i] = wpre[w] + (v - x);              // exclusive prefix
      rdeg[i] = 1.0f / fmaxf((float)x, 1.0f);  // 1/max(deg,1)
    }
    __syncthreads();
  }
}

__global__ __launch_bounds__(256) void fill_b_kernel(const int* __restrict__ srcA,
                                                     const int* __restrict__ dstA,
                                                     const int* __restrict__ srcB,
                                                     const int* __restrict__ dstB,
                                                     const int* __restrict__ offbase,
                                                     int* __restrict__ degbase,
                                                     int* __restrict__ eid_sb,
                                                     int* __restrict__ esrc_sb, int E) {
  const int g = blockIdx.y;
  const int* src = g ? srcB : srcA;
  const int* dst = g ? dstB : dstA;
  const int* off = offbase + (size_t)g * NN;
  int* cursor = degbase + (size_t)g * 2 * NN + NN;
  int* eid_s = eid_sb + (size_t)g * E;
  int* esrc_s = esrc_sb + (size_t)g * E;
  int e = blockIdx.x * 256 + threadIdx.x;
  if (e < E) {
    int d = dst[e];
    int p = off[d] + atomicAdd(&cursor[d], 1);
    eid_s[p] = e;
    esrc_s[p] = src[e];
  }
}

// -------- pass A: h[n] = rdeg * segsum(inputs[eid], dst); f32 in -> bf16 out (128 feats) --------
__global__ __launch_bounds__(256) void gatherA_b_kernel(
    const float* __restrict__ featA, const float* __restrict__ featB,
    const int* __restrict__ gidxb, const int* __restrict__ offbase,
    const int* __restrict__ degbase, const float* __restrict__ rdegbase,
    u32* __restrict__ outbfb /* [2][N*64] */, int E) {
  const int g = blockIdx.y;
  const float* feat = g ? featB : featA;
  const int* gidx = gidxb + (size_t)g * E;
  const int* off = offbase + (size_t)g * NN;
  const int* degi = degbase + (size_t)g * 2 * NN;
  const float* rdeg = rdegbase + (size_t)g * NN;
  u32* outbf = outbfb + (size_t)g * NN * 64;
  const int n = (blockIdx.x << 2) + (threadIdx.x >> 6);
  const int lane = threadIdx.x & 63;
  const int hl = lane & 31, h = lane >> 5;
  const int o = off[n], d = degi[n];
  float4 acc = make_float4(0.f, 0.f, 0.f, 0.f);
  for (int c0 = 0; c0 < d; c0 += 64) {
    const int m = min(64, d - c0);
    const int gg = (lane < m) ? gidx[o + c0 + lane] : 0;
    const int pairs = (m + 1) >> 1;
#pragma unroll 2
    for (int i = 0; i < pairs; ++i) {
      const int e = 2 * i + h;
      const int s = __shfl(gg, e < m ? e : (m - 1));
      const float wgt = (e < m) ? 1.f : 0.f;
      const float4 v = *(const float4*)&feat[(size_t)s * 128 + (hl << 2)];
      acc.x = fmaf(v.x, wgt, acc.x);
      acc.y = fmaf(v.y, wgt, acc.y);
      acc.z = fmaf(v.z, wgt, acc.z);
      acc.w = fmaf(v.w, wgt, acc.w);
    }
  }
  acc.x += __shfl(acc.x, lane ^ 32);
  acc.y += __shfl(acc.y, lane ^ 32);
  acc.z += __shfl(acc.z, lane ^ 32);
  acc.w += __shfl(acc.w, lane ^ 32);
  if (h == 0) {
    const float sc = rdeg[n];
    uint2 r;
    r.x = pack2(acc.x * sc, acc.y * sc);
    r.y = pack2(acc.z * sc, acc.w * sc);
    *(uint2*)&outbf[(size_t)n * 64 + (hl << 1)] = r;
  }
}

// -------- pass B: h2[n] = segsum(h[src]); bf16 table (128 feats, 256B rows) --------
__global__ __launch_bounds__(256) void gatherB_b_kernel(
    const u32* __restrict__ featb /* [2][N*64] */, const int* __restrict__ gidxb,
    const int* __restrict__ offbase, const int* __restrict__ degbase,
    u32* __restrict__ outbfb, int E) {
  const int g = blockIdx.y;
  const u32* feat = featb + (size_t)g * NN * 64;
  const int* gidx = gidxb + (size_t)g * E;
  const int* off = offbase + (size_t)g * NN;
  const int* degi = degbase + (size_t)g * 2 * NN;
  u32* outbf = outbfb + (size_t)g * NN * 64;
  const int n = (blockIdx.x << 2) + (threadIdx.x >> 6);
  const int lane = threadIdx.x & 63;
  const int hl = lane & 31, h = lane >> 5;
  const int o = off[n], d = degi[n];
  float4 acc = make_float4(0.f, 0.f, 0.f, 0.f);
  for (int c0 = 0; c0 < d; c0 += 64) {
    const int m = min(64, d - c0);
    const int gg = (lane < m) ? gidx[o + c0 + lane] : 0;
    const int pairs = (m + 1) >> 1;
#pragma unroll 2
    for (int i = 0; i < pairs; ++i) {
      const int e = 2 * i + h;
      const int s = __shfl(gg, e < m ? e : (m - 1));
      const float wgt = (e < m) ? 1.f : 0.f;
      const uint2 v = *(const uint2*)&feat[(size_t)s * 64 + (hl << 1)];
      acc.x = fmaf(bf_lo(v.x), wgt, acc.x);
      acc.y = fmaf(bf_hi(v.x), wgt, acc.y);
      acc.z = fmaf(bf_lo(v.y), wgt, acc.z);
      acc.w = fmaf(bf_hi(v.y), wgt, acc.w);
    }
  }
  acc.x += __shfl(acc.x, lane ^ 32);
  acc.y += __shfl(acc.y, lane ^ 32);
  acc.z += __shfl(acc.z, lane ^ 32);
  acc.w += __shfl(acc.w, lane ^ 32);
  if (h == 0) {
    uint2 r;
    r.x = pack2(acc.x, acc.y);
    r.y = pack2(acc.z, acc.w);
    *(uint2*)&outbf[(size_t)n * 64 + (hl << 1)] = r;
  }
}

// ---- 8-feat edge accumulate for 256-wide passes ----
__device__ __forceinline__ void acc_bf8(float4& aL, float4& aH, uint4 v,
                                        const float4& znL, const float4& znH,
                                        const float4& bL, const float4& bH, float wgt) {
  aL.x += wgt * lrelu(0.5f * (bf_lo(v.x) + znL.x) + bL.x);
  aL.y += wgt * lrelu(0.5f * (bf_hi(v.x) + znL.y) + bL.y);
  aL.z += wgt * lrelu(0.5f * (bf_lo(v.y) + znL.z) + bL.z);
  aL.w += wgt * lrelu(0.5f * (bf_hi(v.y) + znL.w) + bL.w);
  aH.x += wgt * lrelu(0.5f * (bf_lo(v.z) + znH.x) + bH.x);
  aH.y += wgt * lrelu(0.5f * (bf_hi(v.z) + znH.y) + bH.y);
  aH.z += wgt * lrelu(0.5f * (bf_lo(v.w) + znH.z) + bH.z);
  aH.w += wgt * lrelu(0.5f * (bf_hi(v.w) + znH.w) + bH.w);
}

// -------- pass C: hB[n] = rdeg[n] * sum_e LR(0.5*(Z[src]+Z[n]) + b); Z bf16 [N][256] --------
__global__ __launch_bounds__(256) void passC_b_kernel(
    const u32* __restrict__ Zb_, const int* __restrict__ esrcb,
    const int* __restrict__ offbase, const int* __restrict__ degbase,
    const float* __restrict__ rdegbase,
    const float* __restrict__ biasA, const float* __restrict__ biasB,
    u32* __restrict__ hBb, int E) {
  const int g = blockIdx.y;
  const u32* Z = Zb_ + (size_t)g * NN * 128;
  const int* esrc = esrcb + (size_t)g * E;
  const int* off = offbase + (size_t)g * NN;
  const int* degi = degbase + (size_t)g * 2 * NN;
  const float* rdeg = rdegbase + (size_t)g * NN;
  const float* bias = g ? biasB : biasA;
  u32* hB = hBb + (size_t)g * NN * 128;
  const int n = (blockIdx.x << 2) + (threadIdx.x >> 6);
  const int lane = threadIdx.x & 63;
  const int hl = lane & 31, h = lane >> 5;
  const int o = off[n], d = degi[n];
  const uint4 znv = *(const uint4*)&Z[(size_t)n * 128 + (hl << 2)];
  const float4 znL = make_float4(bf_lo(znv.x), bf_hi(znv.x), bf_lo(znv.y), bf_hi(znv.y));
  const float4 znH = make_float4(bf_lo(znv.z), bf_hi(znv.z), bf_lo(znv.w), bf_hi(znv.w));
  const float4 bL = *(const float4*)&bias[hl << 3];
  const float4 bH = *(const float4*)&bias[(hl << 3) + 4];
  float4 aL = make_float4(0.f, 0.f, 0.f, 0.f), aH = make_float4(0.f, 0.f, 0.f, 0.f);
  for (int c0 = 0; c0 < d; c0 += 64) {
    const int m = min(64, d - c0);
    const int gg = (lane < m) ? esrc[o + c0 + lane] : 0;
    const int pairs = (m + 1) >> 1;
#pragma unroll 2
    for (int i = 0; i < pairs; ++i) {
      const int e = 2 * i + h;
      const int s = __shfl(gg, e < m ? e : (m - 1));
      const float wgt = (e < m) ? 1.f : 0.f;
      const uint4 z = *(const uint4*)&Z[(size_t)s * 128 + (hl << 2)];
      acc_bf8(aL, aH, z, znL, znH, bL, bH, wgt);
    }
  }
  aL.x += __shfl(aL.x, lane ^ 32); aL.y += __shfl(aL.y, lane ^ 32);
  aL.z += __shfl(aL.z, lane ^ 32); aL.w += __shfl(aL.w, lane ^ 32);
  aH.x += __shfl(aH.x, lane ^ 32); aH.y += __shfl(aH.y, lane ^ 32);
  aH.z += __shfl(aH.z, lane ^ 32); aH.w += __shfl(aH.w, lane ^ 32);
  if (h == 0) {
    const float r = rdeg[n];
    uint4 outv;
    outv.x = pack2(aL.x * r, aL.y * r);
    outv.y = pack2(aL.z * r, aL.w * r);
    outv.z = pack2(aH.x * r, aH.y * r);
    outv.w = pack2(aH.z * r, aH.w * r);
    *(uint4*)&hB[(size_t)n * 128 + (hl << 2)] = outv;
  }
}

// -------- gather 256-wide bf16: h2B[n] = segsum(hB[src]) --------
__global__ __launch_bounds__(256) void gatherC_b_kernel(
    const u32* __restrict__ featb /* [2][N*128] */, const int* __restrict__ gidxb,
    const int* __restrict__ offbase, const int* __restrict__ degbase,
    u32* __restrict__ outbfb, int E) {
  const int g = blockIdx.y;
  const u32* feat = featb + (size_t)g * NN * 128;
  const int* gidx = gidxb + (size_t)g * E;
  const int* off = offbase + (size_t)g * NN;
  const int* degi = degbase + (size_t)g * 2 * NN;
  u32* outbf = outbfb + (size_t)g * NN * 128;
  const int n = (blockIdx.x << 2) + (threadIdx.x >> 6);
  const int lane = threadIdx.x & 63;
  const int hl = lane & 31, h = lane >> 5;
  const int o = off[n], d = degi[n];
  float4 aL = make_float4(0.f, 0.f, 0.f, 0.f), aH = make_float4(0.f, 0.f, 0.f, 0.f);
  for (int c0 = 0; c0 < d; c0 += 64) {
    const int m = min(64, d - c0);
    const int gg = (lane < m) ? gidx[o + c0 + lane] : 0;
    const int pairs = (m + 1) >> 1;
#pragma unroll 2
    for (int i = 0; i < pairs; ++i) {
      const int e = 2 * i + h;
      const int s = __shfl(gg, e < m ? e : (m - 1));
      const float wgt = (e < m) ? 1.f : 0.f;
      const uint4 z = *(const uint4*)&feat[(size_t)s * 128 + (hl << 2)];
      aL.x = fmaf(bf_lo(z.x), wgt, aL.x);
      aL.y = fmaf(bf_hi(z.x), wgt, aL.y);
      aL.z = fmaf(bf_lo(z.y), wgt, aL.z);
      aL.w = fmaf(bf_hi(z.y), wgt, aL.w);
      aH.x = fmaf(bf_lo(z.z), wgt, aH.x);
      aH.y = fmaf(bf_hi(z.z), wgt, aH.y);
      aH.z = fmaf(bf_lo(z.w), wgt, aH.z);
      aH.w = fmaf(bf_hi(z.w), wgt, aH.w);
    }
  }
  aL.x += __shfl(aL.x, lane ^ 32); aL.y += __shfl(aL.y, lane ^ 32);
  aL.z += __shfl(aL.z, lane ^ 32); aL.w += __shfl(aL.w, lane ^ 32);
  aH.x += __shfl(aH.x, lane ^ 32); aH.y += __shfl(aH.y, lane ^ 32);
  aH.z += __shfl(aH.z, lane ^ 32); aH.w += __shfl(aH.w, lane ^ 32);
  if (h == 0) {
    uint4 outv;
    outv.x = pack2(aL.x, aL.y);
    outv.y = pack2(aL.z, aL.w);
    outv.z = pack2(aH.x, aH.y);
    outv.w = pack2(aH.z, aH.w);
    *(uint4*)&outbf[(size_t)n * 128 + (hl << 2)] = outv;
  }
}

// -------- pass E: per-block partial sums of LR(0.5*(Z2[src]+Z2[n]) + b) over all edges --------
__global__ __launch_bounds__(256) void passE_b_kernel(
    const u32* __restrict__ Z2b, const int* __restrict__ esrcb,
    const int* __restrict__ offbase, const int* __restrict__ degbase,
    const float* __restrict__ biasA, const float* __restrict__ biasB,
    float* __restrict__ partialsb /* [2][256][256] */, int nNodes, int E) {
  const int g = blockIdx.y;
  const u32* Z2 = Z2b + (size_t)g * NN * 128;
  const int* esrc = esrcb + (size_t)g * E;
  const int* off = offbase + (size_t)g * NN;
  const int* degi = degbase + (size_t)g * 2 * NN;
  const float* bias = g ? biasB : biasA;
  float* partials = partialsb + (size_t)g * 256 * 256;
  const int lane = threadIdx.x & 63, w = threadIdx.x >> 6;
  const int hl = lane & 31, h = lane >> 5;
  const int gw = blockIdx.x * 4 + w, nw = gridDim.x * 4;
  const float4 bL = *(const float4*)&bias[hl << 3];
  const float4 bH = *(const float4*)&bias[(hl << 3) + 4];
  float4 aL = make_float4(0.f, 0.f, 0.f, 0.f), aH = make_float4(0.f, 0.f, 0.f, 0.f);
  for (int n = gw; n < nNodes; n += nw) {
    const int o = off[n], d = degi[n];
    const uint4 znv = *(const uint4*)&Z2[(size_t)n * 128 + (hl << 2)];
    const float4 znL = make_float4(bf_lo(znv.x), bf_hi(znv.x), bf_lo(znv.y), bf_hi(znv.y));
    const float4 znH = make_float4(bf_lo(znv.z), bf_hi(znv.z), bf_lo(znv.w), bf_hi(znv.w));
    for (int c0 = 0; c0 < d; c0 += 64) {
      const int m = min(64, d - c0);
      const int gg = (lane < m) ? esrc[o + c0 + lane] : 0;
      const int pairs = (m + 1) >> 1;
#pragma unroll 2
      for (int i = 0; i < pairs; ++i) {
        const int e = 2 * i + h;
        const int s = __shfl(gg, e < m ? e : (m - 1));
        const float wgt = (e < m) ? 1.f : 0.f;
        const uint4 z = *(const uint4*)&Z2[(size_t)s * 128 + (hl << 2)];
        acc_bf8(aL, aH, z, znL, znH, bL, bH, wgt);
      }
    }
  }
  aL.x += __shfl(aL.x, lane ^ 32); aL.y += __shfl(aL.y, lane ^ 32);
  aL.z += __shfl(aL.z, lane ^ 32); aL.w += __shfl(aL.w, lane ^ 32);
  aH.x += __shfl(aH.x, lane ^ 32); aH.y += __shfl(aH.y, lane ^ 32);
  aH.z += __shfl(aH.z, lane ^ 32); aH.w += __shfl(aH.w, lane ^ 32);
  __shared__ float red[4][256];
  if (h == 0) {
    *(float4*)&red[w][hl << 3] = aL;
    *(float4*)&red[w][(hl << 3) + 4] = aH;
  }
  __syncthreads();
  if (w == 0) {
    float4 s0 = *(const float4*)&red[0][lane << 2];
    float4 s1 = *(const float4*)&red[1][lane << 2];
    float4 s2 = *(const float4*)&red[2][lane << 2];
    float4 s3 = *(const float4*)&red[3][lane << 2];
    float4 s = make_float4(s0.x + s1.x + s2.x + s3.x, s0.y + s1.y + s2.y + s3.y,
                           s0.z + s1.z + s2.z + s3.z, s0.w + s1.w + s2.w + s3.w);
    *(float4*)&partials[(size_t)blockIdx.x * 256 + (lane << 2)] = s;
  }
}

// -------- reduce: macc[g][f] = sum_b partials[g][b][f]; 1024 thr, 4-way row split --------
__global__ __launch_bounds__(1024) void reduce_b_kernel(const float* __restrict__ partialsb,
                                                        float* __restrict__ macc) {
  const int g = blockIdx.x;
  const float* P = partialsb + (size_t)g * 256 * 256;
  const int f = threadIdx.x & 255, q = threadIdx.x >> 8;
  float s = 0.f;
  for (int b = q; b < 256; b += 4) s += P[(size_t)b * 256 + f];
  __shared__ float red[4][256];
  red[q][f] = s;
  __syncthreads();
  if (q == 0) macc[(size_t)g * 256 + f] = red[0][f] + red[1][f] + red[2][f] + red[3][f];
}

// -------- MFMA GEMM: C[n][o] = sum_k A[n][k]*W[o][k]; A,W,C bf16; O=256; batched via z --------
template <int K>
__global__ __launch_bounds__(256) void gemm_mfma_b_kernel(const u16* __restrict__ Ab,
                                                          const u16* __restrict__ WA,
                                                          const u16* __restrict__ WB,
                                                          u16* __restrict__ Cb, int N) {
  const int g = blockIdx.z;
  const u16* A = Ab + (size_t)g * NN * K;
  const u16* Wb = g ? WB : WA;
  u16* C = Cb + (size_t)g * NN * 256;
  const int lane = threadIdx.x & 63;
  const int w = threadIdx.x >> 6;
  const int wm = w >> 1, wn = w & 1;
  const int bn = blockIdx.x * 64 + wm * 32;
  const int bo = blockIdx.y * 64 + wn * 32;
  const int r0 = lane & 15;  // A-row / B-col within 16-tile
  const int kq = lane >> 4;  // k-quarter: 8 elems each
  const int ra0 = min(bn + r0, N - 1);
  const int ra1 = min(bn + 16 + r0, N - 1);
  const u16* a0p = &A[(size_t)ra0 * K + kq * 8];
  const u16* a1p = &A[(size_t)ra1 * K + kq * 8];
  const u16* b0p = &Wb[(size_t)(bo + r0) * K + kq * 8];
  const u16* b1p = &Wb[(size_t)(bo + 16 + r0) * K + kq * 8];
  f32x4 acc00 = {0.f, 0.f, 0.f, 0.f}, acc01 = {0.f, 0.f, 0.f, 0.f};
  f32x4 acc10 = {0.f, 0.f, 0.f, 0.f}, acc11 = {0.f, 0.f, 0.f, 0.f};
#pragma unroll
  for (int k0 = 0; k0 < K; k0 += 32) {
    const short8 a0 = *(const short8*)(a0p + k0);
    const short8 a1 = *(const short8*)(a1p + k0);
    const short8 b0 = *(const short8*)(b0p + k0);
    const short8 b1 = *(const short8*)(b1p + k0);
    acc00 = __builtin_amdgcn_mfma_f32_16x16x32_bf16(a0, b0, acc00, 0, 0, 0);
    acc01 = __builtin_amdgcn_mfma_f32_16x16x32_bf16(a0, b1, acc01, 0, 0, 0);
    acc10 = __builtin_amdgcn_mfma_f32_16x16x32_bf16(a1, b0, acc10, 0, 0, 0);
    acc11 = __builtin_amdgcn_mfma_f32_16x16x32_bf16(a1, b1, acc11, 0, 0, 0);
  }
  // D layout: row = 4*kq + r (within 16-tile), col = r0
#pragma unroll
  for (int r = 0; r < 4; ++r) {
    const int n0 = bn + 4 * kq + r;
    if (n0 < N) {
      C[(size_t)n0 * 256 + bo + r0] = (u16)(rne_bits(acc00[r]) >> 16);
      C[(size_t)n0 * 256 + bo + 16 + r0] = (u16)(rne_bits(acc01[r]) >> 16);
    }
    const int n1 = bn + 16 + 4 * kq + r;
    if (n1 < N) {
      C[(size_t)n1 * 256 + bo + r0] = (u16)(rne_bits(acc10[r]) >> 16);
      C[(size_t)n1 * 256 + bo + 16 + r0] = (u16)(rne_bits(acc11[r]) >> 16);
    }
  }
}

// -------- final: out[j] = b3[j] + invE * sum_k macc[k] * W3[j][k] --------
__global__ __launch_bounds__(256) void final_kernel(const float* __restrict__ macc,
                                                    const float* __restrict__ W3,
                                                    const float* __restrict__ b3,
                                                    float* __restrict__ out, float invE) {
  __shared__ float red[4][64];
  const int j = threadIdx.x & 63, part = threadIdx.x >> 6;
  float acc = 0.f;
  for (int kk = 0; kk < 128; ++kk) {
    const int k = part * 128 + kk;
    acc += macc[k] * W3[(size_t)j * 512 + k];
  }
  red[part][j] = acc;
  __syncthreads();
  if (part == 0)
    out[j] = b3[j] + (red[0][j] + red[1][j] + red[2][j] + red[3][j]) * invE;
}

extern "C" void kernel_launch(void* const* d_in, const int* in_sizes, int n_in,
                              void* d_out, int out_size, void* d_ws, size_t ws_size,
                              hipStream_t stream) {
  const float* in1 = (const float*)d_in[0];
  const int* src1 = (const int*)d_in[1];
  const int* dst1 = (const int*)d_in[2];
  const float* in2 = (const float*)d_in[3];
  const int* src2 = (const int*)d_in[4];
  const int* dst2 = (const int*)d_in[5];
  const float* W11 = (const float*)d_in[6];
  const float* b11 = (const float*)d_in[7];
  const float* W12 = (const float*)d_in[8];
  const float* b12 = (const float*)d_in[9];
  const float* W21 = (const float*)d_in[10];
  const float* b21 = (const float*)d_in[11];
  const float* W22 = (const float*)d_in[12];
  const float* b22 = (const float*)d_in[13];
  const float* W3 = (const float*)d_in[14];
  const float* b3 = (const float*)d_in[15];
  const int E = in_sizes[1];
  const int N = NN;

  // ---- workspace carve (512B aligned) ----
  char* base = (char*)d_ws;
  size_t pos = 0;
  auto carve = [&](size_t bytes) -> char* {
    char* p = base + pos;
    pos = (pos + bytes + 511) & ~(size_t)511;
    return p;
  };
  int* degbase = (int*)carve((size_t)2 * 2 * N * sizeof(int));  // [g][deg|cursor]
  int* offb = (int*)carve((size_t)2 * N * sizeof(int));
  float* rdegb = (float*)carve((size_t)2 * N * sizeof(float));
  int* eid_sb = (int*)carve((size_t)2 * E * sizeof(int));
  int* esrc_sb = (int*)carve((size_t)2 * E * sizeof(int));
  u32* Hb = (u32*)carve((size_t)2 * N * 64 * sizeof(u32));     // h   (bf16, 128 feats)
  u32* H2b = (u32*)carve((size_t)2 * N * 64 * sizeof(u32));    // h2  (bf16, 128 feats)
  u32* Zb = (u32*)carve((size_t)2 * N * 128 * sizeof(u32));    // Z / Z2 (bf16, 256 feats)
  u32* HBb = (u32*)carve((size_t)2 * N * 128 * sizeof(u32));   // hB  (bf16, 256 feats)
  u32* H2Bb = (u32*)carve((size_t)2 * N * 128 * sizeof(u32));  // h2B (bf16, 256 feats)
  u16* Wa1 = (u16*)carve((size_t)32768 * sizeof(u16));         // W11 bf16
  u16* Wb1 = (u16*)carve((size_t)65536 * sizeof(u16));         // W12 bf16
  u16* Wa2 = (u16*)carve((size_t)32768 * sizeof(u16));         // W21 bf16
  u16* Wb2 = (u16*)carve((size_t)65536 * sizeof(u16));         // W22 bf16
  float* partialsb = (float*)carve((size_t)2 * 256 * 256 * sizeof(float));
  float* macc = (float*)carve((size_t)2 * 256 * sizeof(float));
  (void)ws_size; (void)n_in; (void)out_size;

  const int EB = (E + 255) / 256;  // edge-parallel blocks
  const int NB = N / 4;            // wave-per-node blocks (4 waves/block)
  const dim3 g2(EB, 2);
  const dim3 n2(NB, 2);
  const dim3 gemm_grid((N + 63) / 64, 4, 2);

  wconv_kernel<<<768, 256, 0, stream>>>(W11, W12, W21, W22, Wa1, Wb1, Wa2, Wb2);
  hipMemsetAsync(degbase, 0, (size_t)4 * N * sizeof(int), stream);

  count_b_kernel<<<g2, 256, 0, stream>>>(dst1, dst2, degbase, E);
  scan_b_kernel<<<2, 1024, 0, stream>>>(degbase, offb, rdegb, N);
  fill_b_kernel<<<g2, 256, 0, stream>>>(src1, dst1, src2, dst2, offb, degbase, eid_sb, esrc_sb, E);

  // layer 1: h = segsum(inputs, dst)/deg ; h2 = segsum(h[src], dst) ; Z = h2 @ Wa.T
  gatherA_b_kernel<<<n2, 256, 0, stream>>>(in1, in2, eid_sb, offb, degbase, rdegb, Hb, E);
  gatherB_b_kernel<<<n2, 256, 0, stream>>>(Hb, esrc_sb, offb, degbase, H2b, E);
  gemm_mfma_b_kernel<128><<<gemm_grid, 256, 0, stream>>>((const u16*)H2b, Wa1, Wa2, (u16*)Zb, N);

  // layer 2 input: hB = rdeg * segsum(LR(0.5*(Z[src]+Z[dst])+ba), dst)
  passC_b_kernel<<<n2, 256, 0, stream>>>(Zb, esrc_sb, offb, degbase, rdegb, b11, b21, HBb, E);
  // h2B = segsum(hB[src], dst) ; Z2 = h2B @ Wb.T
  gatherC_b_kernel<<<n2, 256, 0, stream>>>(HBb, esrc_sb, offb, degbase, H2Bb, E);
  gemm_mfma_b_kernel<256><<<gemm_grid, 256, 0, stream>>>((const u16*)H2Bb, Wb1, Wb2, (u16*)Zb, N);

  // mean over edges of LR(0.5*(Z2[src]+Z2[dst])+bb)  (unscaled sum -> macc)
  passE_b_kernel<<<dim3(256, 2), 256, 0, stream>>>(Zb, esrc_sb, offb, degbase, b12, b22,
                                                   partialsb, N, E);
  reduce_b_kernel<<<2, 1024, 0, stream>>>(partialsb, macc);

  final_kernel<<<1, 256, 0, stream>>>(macc, W3, b3, (float*)d_out, 1.0f / (float)E);
}

// Round 5
// 345.245 us; speedup vs baseline: 2.2714x; 1.2082x over previous
//
#include <hip/hip_runtime.h>
#include <cstddef>

#define NN 10000  // N_NODES

typedef unsigned int u32;
typedef unsigned short u16;
typedef __attribute__((ext_vector_type(8))) short short8;
typedef __attribute__((ext_vector_type(4))) float f32x4;

__device__ __forceinline__ float lrelu(float x) { return x >= 0.f ? x : 0.01f * x; }

// ---- bf16 helpers (tables stored bf16, math in f32) ----
__device__ __forceinline__ float bf_lo(u32 v) { union { u32 i; float f; } c; c.i = v << 16; return c.f; }
__device__ __forceinline__ float bf_hi(u32 v) { union { u32 i; float f; } c; c.i = v & 0xFFFF0000u; return c.f; }
__device__ __forceinline__ u32 rne_bits(float f) {
  union { float f; u32 i; } c; c.f = f;
  return c.i + 0x7FFFu + ((c.i >> 16) & 1u);
}
__device__ __forceinline__ u32 pack2(float a, float b) {
  return (rne_bits(a) >> 16) | (rne_bits(b) & 0xFFFF0000u);
}

// ---------------- weight convert + workspace zero ----------------
__global__ __launch_bounds__(256) void wconv_kernel(
    const float* __restrict__ a, const float* __restrict__ b,
    const float* __restrict__ c, const float* __restrict__ d,
    u16* __restrict__ oa, u16* __restrict__ ob,
    u16* __restrict__ oc, u16* __restrict__ od,
    int* __restrict__ degbase /* 4*NN ints to zero */) {
  int i = blockIdx.x * 256 + threadIdx.x;  // grid covers 196608
  if (i < 32768) oa[i] = (u16)(rne_bits(a[i]) >> 16);
  else if (i < 98304) ob[i - 32768] = (u16)(rne_bits(b[i - 32768]) >> 16);
  else if (i < 131072) oc[i - 98304] = (u16)(rne_bits(c[i - 98304]) >> 16);
  else if (i < 196608) od[i - 131072] = (u16)(rne_bits(d[i - 131072]) >> 16);
  if (i < 4 * NN) degbase[i] = 0;
}

// ---------------- CSR build (batched over 2 graphs via blockIdx.y) ----------------
__global__ __launch_bounds__(256) void count_b_kernel(const int* __restrict__ dstA,
                                                      const int* __restrict__ dstB,
                                                      int* __restrict__ degbase, int E) {
  const int g = blockIdx.y;
  const int* dst = g ? dstB : dstA;
  int* degi = degbase + (size_t)g * 2 * NN;
  int e = blockIdx.x * 256 + threadIdx.x;
  if (e < E) atomicAdd(&degi[dst[e]], 1);
}

__global__ __launch_bounds__(1024) void scan_b_kernel(const int* __restrict__ degbase,
                                                      int* __restrict__ offbase,
                                                      float* __restrict__ rdegbase, int n) {
  const int g = blockIdx.x;
  const int* degi = degbase + (size_t)g * 2 * NN;
  int* off = offbase + (size_t)g * NN;
  float* rdeg = rdegbase + (size_t)g * NN;
  __shared__ int wsum[16];
  __shared__ int wpre[16];
  __shared__ int carry_s;
  const int tid = threadIdx.x;
  const int lane = tid & 63, w = tid >> 6;
  if (tid == 0) carry_s = 0;
  __syncthreads();
  for (int base = 0; base < n; base += 1024) {
    int i = base + tid;
    int x = (i < n) ? degi[i] : 0;
    int v = x;
#pragma unroll
    for (int d = 1; d < 64; d <<= 1) {
      int t = __shfl_up(v, d);
      if (lane >= d) v += t;
    }
    if (lane == 63) wsum[w] = v;
    __syncthreads();
    if (tid == 0) {
      int s = carry_s;
#pragma unroll
      for (int j = 0; j < 16; ++j) { int t = wsum[j]; wpre[j] = s; s += t; }
      carry_s = s;
    }
    __syncthreads();
    if (i < n) {
      off[i] = wpre[w] + (v - x);              // exclusive prefix
      rdeg[i] = 1.0f / fmaxf((float)x, 1.0f);  // 1/max(deg,1)
    }
    __syncthreads();
  }
}

__global__ __launch_bounds__(256) void fill_b_kernel(const int* __restrict__ srcA,
                                                     const int* __restrict__ dstA,
                                                     const int* __restrict__ srcB,
                                                     const int* __restrict__ dstB,
                                                     const int* __restrict__ offbase,
                                                     int* __restrict__ degbase,
                                                     int* __restrict__ eid_sb,
                                                     int* __restrict__ esrc_sb, int E) {
  const int g = blockIdx.y;
  const int* src = g ? srcB : srcA;
  const int* dst = g ? dstB : dstA;
  const int* off = offbase + (size_t)g * NN;
  int* cursor = degbase + (size_t)g * 2 * NN + NN;
  int* eid_s = eid_sb + (size_t)g * E;
  int* esrc_s = esrc_sb + (size_t)g * E;
  int e = blockIdx.x * 256 + threadIdx.x;
  if (e < E) {
    int d = dst[e];
    int p = off[d] + atomicAdd(&cursor[d], 1);
    eid_s[p] = e;
    esrc_s[p] = src[e];
  }
}

// -------- pass A: h[n] = rdeg * segsum(inputs[eid], dst); f32 in -> bf16 out (128 feats) --------
// half-wave: 32 lanes x float4 = full 512B row; halves take alternate edges; 4 loads in flight.
__global__ __launch_bounds__(256) void gatherA_b_kernel(
    const float* __restrict__ featA, const float* __restrict__ featB,
    const int* __restrict__ gidxb, const int* __restrict__ offbase,
    const int* __restrict__ degbase, const float* __restrict__ rdegbase,
    u32* __restrict__ outbfb /* [2][N*64] */, int E) {
  const int g = blockIdx.y;
  const float* feat = g ? featB : featA;
  const int* gidx = gidxb + (size_t)g * E;
  const int* off = offbase + (size_t)g * NN;
  const int* degi = degbase + (size_t)g * 2 * NN;
  const float* rdeg = rdegbase + (size_t)g * NN;
  u32* outbf = outbfb + (size_t)g * NN * 64;
  const int n = (blockIdx.x << 2) + (threadIdx.x >> 6);
  const int lane = threadIdx.x & 63;
  const int hl = lane & 31, h = lane >> 5;
  const int o = off[n], d = degi[n];
  const int fo = hl << 2;
  float4 acc = make_float4(0.f, 0.f, 0.f, 0.f);
  for (int c0 = 0; c0 < d; c0 += 64) {
    const int m = min(64, d - c0);
    const int gg = (lane < m) ? gidx[o + c0 + lane] : 0;
    const int pairs = m >> 1;  // full pairs: both halves in-range, no guards
    int i = 0;
    for (; i + 4 <= pairs; i += 4) {
      const int e0 = 2 * i + h;
      const int s0 = __shfl(gg, e0), s1 = __shfl(gg, e0 + 2);
      const int s2 = __shfl(gg, e0 + 4), s3 = __shfl(gg, e0 + 6);
      const float4 v0 = *(const float4*)&feat[(s0 << 7) + fo];
      const float4 v1 = *(const float4*)&feat[(s1 << 7) + fo];
      const float4 v2 = *(const float4*)&feat[(s2 << 7) + fo];
      const float4 v3 = *(const float4*)&feat[(s3 << 7) + fo];
      acc.x += (v0.x + v1.x) + (v2.x + v3.x);
      acc.y += (v0.y + v1.y) + (v2.y + v3.y);
      acc.z += (v0.z + v1.z) + (v2.z + v3.z);
      acc.w += (v0.w + v1.w) + (v2.w + v3.w);
    }
    for (; i < pairs; ++i) {
      const int s0 = __shfl(gg, 2 * i + h);
      const float4 v0 = *(const float4*)&feat[(s0 << 7) + fo];
      acc.x += v0.x; acc.y += v0.y; acc.z += v0.z; acc.w += v0.w;
    }
    if (m & 1) {  // odd tail: edge m-1, counted once (half 0)
      const int s0 = __shfl(gg, m - 1);
      const float wgt = (h == 0) ? 1.f : 0.f;
      const float4 v0 = *(const float4*)&feat[(s0 << 7) + fo];
      acc.x = fmaf(v0.x, wgt, acc.x);
      acc.y = fmaf(v0.y, wgt, acc.y);
      acc.z = fmaf(v0.z, wgt, acc.z);
      acc.w = fmaf(v0.w, wgt, acc.w);
    }
  }
  acc.x += __shfl(acc.x, lane ^ 32);
  acc.y += __shfl(acc.y, lane ^ 32);
  acc.z += __shfl(acc.z, lane ^ 32);
  acc.w += __shfl(acc.w, lane ^ 32);
  if (h == 0) {
    const float sc = rdeg[n];
    uint2 r;
    r.x = pack2(acc.x * sc, acc.y * sc);
    r.y = pack2(acc.z * sc, acc.w * sc);
    *(uint2*)&outbf[(size_t)n * 64 + (hl << 1)] = r;
  }
}

// -------- pass B: h2[n] = segsum(h[src]); bf16 table (128 feats, 256B rows) --------
__global__ __launch_bounds__(256) void gatherB_b_kernel(
    const u32* __restrict__ featb /* [2][N*64] */, const int* __restrict__ gidxb,
    const int* __restrict__ offbase, const int* __restrict__ degbase,
    u32* __restrict__ outbfb, int E) {
  const int g = blockIdx.y;
  const u32* feat = featb + (size_t)g * NN * 64;
  const int* gidx = gidxb + (size_t)g * E;
  const int* off = offbase + (size_t)g * NN;
  const int* degi = degbase + (size_t)g * 2 * NN;
  u32* outbf = outbfb + (size_t)g * NN * 64;
  const int n = (blockIdx.x << 2) + (threadIdx.x >> 6);
  const int lane = threadIdx.x & 63;
  const int hl = lane & 31, h = lane >> 5;
  const int o = off[n], d = degi[n];
  const int fo = hl << 1;
  float4 acc = make_float4(0.f, 0.f, 0.f, 0.f);
  for (int c0 = 0; c0 < d; c0 += 64) {
    const int m = min(64, d - c0);
    const int gg = (lane < m) ? gidx[o + c0 + lane] : 0;
    const int pairs = m >> 1;
    int i = 0;
    for (; i + 4 <= pairs; i += 4) {
      const int e0 = 2 * i + h;
      const int s0 = __shfl(gg, e0), s1 = __shfl(gg, e0 + 2);
      const int s2 = __shfl(gg, e0 + 4), s3 = __shfl(gg, e0 + 6);
      const uint2 v0 = *(const uint2*)&feat[(s0 << 6) + fo];
      const uint2 v1 = *(const uint2*)&feat[(s1 << 6) + fo];
      const uint2 v2 = *(const uint2*)&feat[(s2 << 6) + fo];
      const uint2 v3 = *(const uint2*)&feat[(s3 << 6) + fo];
      acc.x += (bf_lo(v0.x) + bf_lo(v1.x)) + (bf_lo(v2.x) + bf_lo(v3.x));
      acc.y += (bf_hi(v0.x) + bf_hi(v1.x)) + (bf_hi(v2.x) + bf_hi(v3.x));
      acc.z += (bf_lo(v0.y) + bf_lo(v1.y)) + (bf_lo(v2.y) + bf_lo(v3.y));
      acc.w += (bf_hi(v0.y) + bf_hi(v1.y)) + (bf_hi(v2.y) + bf_hi(v3.y));
    }
    for (; i < pairs; ++i) {
      const int s0 = __shfl(gg, 2 * i + h);
      const uint2 v0 = *(const uint2*)&feat[(s0 << 6) + fo];
      acc.x += bf_lo(v0.x); acc.y += bf_hi(v0.x);
      acc.z += bf_lo(v0.y); acc.w += bf_hi(v0.y);
    }
    if (m & 1) {
      const int s0 = __shfl(gg, m - 1);
      const float wgt = (h == 0) ? 1.f : 0.f;
      const uint2 v0 = *(const uint2*)&feat[(s0 << 6) + fo];
      acc.x = fmaf(bf_lo(v0.x), wgt, acc.x);
      acc.y = fmaf(bf_hi(v0.x), wgt, acc.y);
      acc.z = fmaf(bf_lo(v0.y), wgt, acc.z);
      acc.w = fmaf(bf_hi(v0.y), wgt, acc.w);
    }
  }
  acc.x += __shfl(acc.x, lane ^ 32);
  acc.y += __shfl(acc.y, lane ^ 32);
  acc.z += __shfl(acc.z, lane ^ 32);
  acc.w += __shfl(acc.w, lane ^ 32);
  if (h == 0) {
    uint2 r;
    r.x = pack2(acc.x, acc.y);
    r.y = pack2(acc.z, acc.w);
    *(uint2*)&outbf[(size_t)n * 64 + (hl << 1)] = r;
  }
}

// ---- 8-feat edge accumulate for 256-wide passes ----
__device__ __forceinline__ void acc_bf8n(float4& aL, float4& aH, uint4 v,
                                         const float4& znL, const float4& znH,
                                         const float4& bL, const float4& bH) {
  aL.x += lrelu(0.5f * (bf_lo(v.x) + znL.x) + bL.x);
  aL.y += lrelu(0.5f * (bf_hi(v.x) + znL.y) + bL.y);
  aL.z += lrelu(0.5f * (bf_lo(v.y) + znL.z) + bL.z);
  aL.w += lrelu(0.5f * (bf_hi(v.y) + znL.w) + bL.w);
  aH.x += lrelu(0.5f * (bf_lo(v.z) + znH.x) + bH.x);
  aH.y += lrelu(0.5f * (bf_hi(v.z) + znH.y) + bH.y);
  aH.z += lrelu(0.5f * (bf_lo(v.w) + znH.z) + bH.z);
  aH.w += lrelu(0.5f * (bf_hi(v.w) + znH.w) + bH.w);
}
__device__ __forceinline__ void acc_bf8w(float4& aL, float4& aH, uint4 v,
                                         const float4& znL, const float4& znH,
                                         const float4& bL, const float4& bH, float wgt) {
  aL.x += wgt * lrelu(0.5f * (bf_lo(v.x) + znL.x) + bL.x);
  aL.y += wgt * lrelu(0.5f * (bf_hi(v.x) + znL.y) + bL.y);
  aL.z += wgt * lrelu(0.5f * (bf_lo(v.y) + znL.z) + bL.z);
  aL.w += wgt * lrelu(0.5f * (bf_hi(v.y) + znL.w) + bL.w);
  aH.x += wgt * lrelu(0.5f * (bf_lo(v.z) + znH.x) + bH.x);
  aH.y += wgt * lrelu(0.5f * (bf_hi(v.z) + znH.y) + bH.y);
  aH.z += wgt * lrelu(0.5f * (bf_lo(v.w) + znH.z) + bH.z);
  aH.w += wgt * lrelu(0.5f * (bf_hi(v.w) + znH.w) + bH.w);
}

// -------- pass C: hB[n] = rdeg[n] * sum_e LR(0.5*(Z[src]+Z[n]) + b); Z bf16 [N][256] --------
__global__ __launch_bounds__(256) void passC_b_kernel(
    const u32* __restrict__ Zb_, const int* __restrict__ esrcb,
    const int* __restrict__ offbase, const int* __restrict__ degbase,
    const float* __restrict__ rdegbase,
    const float* __restrict__ biasA, const float* __restrict__ biasB,
    u32* __restrict__ hBb, int E) {
  const int g = blockIdx.y;
  const u32* Z = Zb_ + (size_t)g * NN * 128;
  const int* esrc = esrcb + (size_t)g * E;
  const int* off = offbase + (size_t)g * NN;
  const int* degi = degbase + (size_t)g * 2 * NN;
  const float* rdeg = rdegbase + (size_t)g * NN;
  const float* bias = g ? biasB : biasA;
  u32* hB = hBb + (size_t)g * NN * 128;
  const int n = (blockIdx.x << 2) + (threadIdx.x >> 6);
  const int lane = threadIdx.x & 63;
  const int hl = lane & 31, h = lane >> 5;
  const int o = off[n], d = degi[n];
  const int fo = hl << 2;
  const uint4 znv = *(const uint4*)&Z[(n << 7) + fo];
  const float4 znL = make_float4(bf_lo(znv.x), bf_hi(znv.x), bf_lo(znv.y), bf_hi(znv.y));
  const float4 znH = make_float4(bf_lo(znv.z), bf_hi(znv.z), bf_lo(znv.w), bf_hi(znv.w));
  const float4 bL = *(const float4*)&bias[hl << 3];
  const float4 bH = *(const float4*)&bias[(hl << 3) + 4];
  float4 aL = make_float4(0.f, 0.f, 0.f, 0.f), aH = make_float4(0.f, 0.f, 0.f, 0.f);
  for (int c0 = 0; c0 < d; c0 += 64) {
    const int m = min(64, d - c0);
    const int gg = (lane < m) ? esrc[o + c0 + lane] : 0;
    const int pairs = m >> 1;
    int i = 0;
    for (; i + 4 <= pairs; i += 4) {
      const int e0 = 2 * i + h;
      const int s0 = __shfl(gg, e0), s1 = __shfl(gg, e0 + 2);
      const int s2 = __shfl(gg, e0 + 4), s3 = __shfl(gg, e0 + 6);
      const uint4 z0 = *(const uint4*)&Z[(s0 << 7) + fo];
      const uint4 z1 = *(const uint4*)&Z[(s1 << 7) + fo];
      const uint4 z2 = *(const uint4*)&Z[(s2 << 7) + fo];
      const uint4 z3 = *(const uint4*)&Z[(s3 << 7) + fo];
      acc_bf8n(aL, aH, z0, znL, znH, bL, bH);
      acc_bf8n(aL, aH, z1, znL, znH, bL, bH);
      acc_bf8n(aL, aH, z2, znL, znH, bL, bH);
      acc_bf8n(aL, aH, z3, znL, znH, bL, bH);
    }
    for (; i < pairs; ++i) {
      const int s0 = __shfl(gg, 2 * i + h);
      const uint4 z0 = *(const uint4*)&Z[(s0 << 7) + fo];
      acc_bf8n(aL, aH, z0, znL, znH, bL, bH);
    }
    if (m & 1) {
      const int s0 = __shfl(gg, m - 1);
      const float wgt = (h == 0) ? 1.f : 0.f;
      const uint4 z0 = *(const uint4*)&Z[(s0 << 7) + fo];
      acc_bf8w(aL, aH, z0, znL, znH, bL, bH, wgt);
    }
  }
  aL.x += __shfl(aL.x, lane ^ 32); aL.y += __shfl(aL.y, lane ^ 32);
  aL.z += __shfl(aL.z, lane ^ 32); aL.w += __shfl(aL.w, lane ^ 32);
  aH.x += __shfl(aH.x, lane ^ 32); aH.y += __shfl(aH.y, lane ^ 32);
  aH.z += __shfl(aH.z, lane ^ 32); aH.w += __shfl(aH.w, lane ^ 32);
  if (h == 0) {
    const float r = rdeg[n];
    uint4 outv;
    outv.x = pack2(aL.x * r, aL.y * r);
    outv.y = pack2(aL.z * r, aL.w * r);
    outv.z = pack2(aH.x * r, aH.y * r);
    outv.w = pack2(aH.z * r, aH.w * r);
    *(uint4*)&hB[(n << 7) + fo] = outv;
  }
}

// -------- gather 256-wide bf16: h2B[n] = segsum(hB[src]) --------
__global__ __launch_bounds__(256) void gatherC_b_kernel(
    const u32* __restrict__ featb /* [2][N*128] */, const int* __restrict__ gidxb,
    const int* __restrict__ offbase, const int* __restrict__ degbase,
    u32* __restrict__ outbfb, int E) {
  const int g = blockIdx.y;
  const u32* feat = featb + (size_t)g * NN * 128;
  const int* gidx = gidxb + (size_t)g * E;
  const int* off = offbase + (size_t)g * NN;
  const int* degi = degbase + (size_t)g * 2 * NN;
  u32* outbf = outbfb + (size_t)g * NN * 128;
  const int n = (blockIdx.x << 2) + (threadIdx.x >> 6);
  const int lane = threadIdx.x & 63;
  const int hl = lane & 31, h = lane >> 5;
  const int o = off[n], d = degi[n];
  const int fo = hl << 2;
  float4 aL = make_float4(0.f, 0.f, 0.f, 0.f), aH = make_float4(0.f, 0.f, 0.f, 0.f);
  for (int c0 = 0; c0 < d; c0 += 64) {
    const int m = min(64, d - c0);
    const int gg = (lane < m) ? gidx[o + c0 + lane] : 0;
    const int pairs = m >> 1;
    int i = 0;
    for (; i + 4 <= pairs; i += 4) {
      const int e0 = 2 * i + h;
      const int s0 = __shfl(gg, e0), s1 = __shfl(gg, e0 + 2);
      const int s2 = __shfl(gg, e0 + 4), s3 = __shfl(gg, e0 + 6);
      const uint4 z0 = *(const uint4*)&feat[(s0 << 7) + fo];
      const uint4 z1 = *(const uint4*)&feat[(s1 << 7) + fo];
      const uint4 z2 = *(const uint4*)&feat[(s2 << 7) + fo];
      const uint4 z3 = *(const uint4*)&feat[(s3 << 7) + fo];
      aL.x += (bf_lo(z0.x) + bf_lo(z1.x)) + (bf_lo(z2.x) + bf_lo(z3.x));
      aL.y += (bf_hi(z0.x) + bf_hi(z1.x)) + (bf_hi(z2.x) + bf_hi(z3.x));
      aL.z += (bf_lo(z0.y) + bf_lo(z1.y)) + (bf_lo(z2.y) + bf_lo(z3.y));
      aL.w += (bf_hi(z0.y) + bf_hi(z1.y)) + (bf_hi(z2.y) + bf_hi(z3.y));
      aH.x += (bf_lo(z0.z) + bf_lo(z1.z)) + (bf_lo(z2.z) + bf_lo(z3.z));
      aH.y += (bf_hi(z0.z) + bf_hi(z1.z)) + (bf_hi(z2.z) + bf_hi(z3.z));
      aH.z += (bf_lo(z0.w) + bf_lo(z1.w)) + (bf_lo(z2.w) + bf_lo(z3.w));
      aH.w += (bf_hi(z0.w) + bf_hi(z1.w)) + (bf_hi(z2.w) + bf_hi(z3.w));
    }
    for (; i < pairs; ++i) {
      const int s0 = __shfl(gg, 2 * i + h);
      const uint4 z0 = *(const uint4*)&feat[(s0 << 7) + fo];
      aL.x += bf_lo(z0.x); aL.y += bf_hi(z0.x);
      aL.z += bf_lo(z0.y); aL.w += bf_hi(z0.y);
      aH.x += bf_lo(z0.z); aH.y += bf_hi(z0.z);
      aH.z += bf_lo(z0.w); aH.w += bf_hi(z0.w);
    }
    if (m & 1) {
      const int s0 = __shfl(gg, m - 1);
      const float wgt = (h == 0) ? 1.f : 0.f;
      const uint4 z0 = *(const uint4*)&feat[(s0 << 7) + fo];
      aL.x = fmaf(bf_lo(z0.x), wgt, aL.x); aL.y = fmaf(bf_hi(z0.x), wgt, aL.y);
      aL.z = fmaf(bf_lo(z0.y), wgt, aL.z); aL.w = fmaf(bf_hi(z0.y), wgt, aL.w);
      aH.x = fmaf(bf_lo(z0.z), wgt, aH.x); aH.y = fmaf(bf_hi(z0.z), wgt, aH.y);
      aH.z = fmaf(bf_lo(z0.w), wgt, aH.z); aH.w = fmaf(bf_hi(z0.w), wgt, aH.w);
    }
  }
  aL.x += __shfl(aL.x, lane ^ 32); aL.y += __shfl(aL.y, lane ^ 32);
  aL.z += __shfl(aL.z, lane ^ 32); aL.w += __shfl(aL.w, lane ^ 32);
  aH.x += __shfl(aH.x, lane ^ 32); aH.y += __shfl(aH.y, lane ^ 32);
  aH.z += __shfl(aH.z, lane ^ 32); aH.w += __shfl(aH.w, lane ^ 32);
  if (h == 0) {
    uint4 outv;
    outv.x = pack2(aL.x, aL.y);
    outv.y = pack2(aL.z, aL.w);
    outv.z = pack2(aH.x, aH.y);
    outv.w = pack2(aH.z, aH.w);
    *(uint4*)&outbf[(n << 7) + fo] = outv;
  }
}

// -------- pass E: per-block partial sums of LR(0.5*(Z2[src]+Z2[n]) + b) over all edges --------
__global__ __launch_bounds__(256) void passE_b_kernel(
    const u32* __restrict__ Z2b, const int* __restrict__ esrcb,
    const int* __restrict__ offbase, const int* __restrict__ degbase,
    const float* __restrict__ biasA, const float* __restrict__ biasB,
    float* __restrict__ partialsb /* [2][256][256] */, int nNodes, int E) {
  const int g = blockIdx.y;
  const u32* Z2 = Z2b + (size_t)g * NN * 128;
  const int* esrc = esrcb + (size_t)g * E;
  const int* off = offbase + (size_t)g * NN;
  const int* degi = degbase + (size_t)g * 2 * NN;
  const float* bias = g ? biasB : biasA;
  float* partials = partialsb + (size_t)g * 256 * 256;
  const int lane = threadIdx.x & 63, w = threadIdx.x >> 6;
  const int hl = lane & 31, h = lane >> 5;
  const int gw = blockIdx.x * 4 + w, nw = gridDim.x * 4;
  const int fo = hl << 2;
  const float4 bL = *(const float4*)&bias[hl << 3];
  const float4 bH = *(const float4*)&bias[(hl << 3) + 4];
  float4 aL = make_float4(0.f, 0.f, 0.f, 0.f), aH = make_float4(0.f, 0.f, 0.f, 0.f);
  for (int n = gw; n < nNodes; n += nw) {
    const int o = off[n], d = degi[n];
    const uint4 znv = *(const uint4*)&Z2[(n << 7) + fo];
    const float4 znL = make_float4(bf_lo(znv.x), bf_hi(znv.x), bf_lo(znv.y), bf_hi(znv.y));
    const float4 znH = make_float4(bf_lo(znv.z), bf_hi(znv.z), bf_lo(znv.w), bf_hi(znv.w));
    for (int c0 = 0; c0 < d; c0 += 64) {
      const int m = min(64, d - c0);
      const int gg = (lane < m) ? esrc[o + c0 + lane] : 0;
      const int pairs = m >> 1;
      int i = 0;
      for (; i + 4 <= pairs; i += 4) {
        const int e0 = 2 * i + h;
        const int s0 = __shfl(gg, e0), s1 = __shfl(gg, e0 + 2);
        const int s2 = __shfl(gg, e0 + 4), s3 = __shfl(gg, e0 + 6);
        const uint4 z0 = *(const uint4*)&Z2[(s0 << 7) + fo];
        const uint4 z1 = *(const uint4*)&Z2[(s1 << 7) + fo];
        const uint4 z2 = *(const uint4*)&Z2[(s2 << 7) + fo];
        const uint4 z3 = *(const uint4*)&Z2[(s3 << 7) + fo];
        acc_bf8n(aL, aH, z0, znL, znH, bL, bH);
        acc_bf8n(aL, aH, z1, znL, znH, bL, bH);
        acc_bf8n(aL, aH, z2, znL, znH, bL, bH);
        acc_bf8n(aL, aH, z3, znL, znH, bL, bH);
      }
      for (; i < pairs; ++i) {
        const int s0 = __shfl(gg, 2 * i + h);
        const uint4 z0 = *(const uint4*)&Z2[(s0 << 7) + fo];
        acc_bf8n(aL, aH, z0, znL, znH, bL, bH);
      }
      if (m & 1) {
        const int s0 = __shfl(gg, m - 1);
        const float wgt = (h == 0) ? 1.f : 0.f;
        const uint4 z0 = *(const uint4*)&Z2[(s0 << 7) + fo];
        acc_bf8w(aL, aH, z0, znL, znH, bL, bH, wgt);
      }
    }
  }
  aL.x += __shfl(aL.x, lane ^ 32); aL.y += __shfl(aL.y, lane ^ 32);
  aL.z += __shfl(aL.z, lane ^ 32); aL.w += __shfl(aL.w, lane ^ 32);
  aH.x += __shfl(aH.x, lane ^ 32); aH.y += __shfl(aH.y, lane ^ 32);
  aH.z += __shfl(aH.z, lane ^ 32); aH.w += __shfl(aH.w, lane ^ 32);
  __shared__ float red[4][256];
  if (h == 0) {
    *(float4*)&red[w][hl << 3] = aL;
    *(float4*)&red[w][(hl << 3) + 4] = aH;
  }
  __syncthreads();
  if (w == 0) {
    float4 s0 = *(const float4*)&red[0][lane << 2];
    float4 s1 = *(const float4*)&red[1][lane << 2];
    float4 s2 = *(const float4*)&red[2][lane << 2];
    float4 s3 = *(const float4*)&red[3][lane << 2];
    float4 s = make_float4(s0.x + s1.x + s2.x + s3.x, s0.y + s1.y + s2.y + s3.y,
                           s0.z + s1.z + s2.z + s3.z, s0.w + s1.w + s2.w + s3.w);
    *(float4*)&partials[(size_t)blockIdx.x * 256 + (lane << 2)] = s;
  }
}

// -------- fused reduce + final: out[j] = b3[j] + invE * sum_k macc[k] * W3[j][k] --------
__global__ __launch_bounds__(1024) void final_fused_kernel(
    const float* __restrict__ partialsb /* [2][256][256] */,
    const float* __restrict__ W3, const float* __restrict__ b3,
    float* __restrict__ out, float invE) {
  __shared__ float smacc[512];     // concat [g*256+k]
  __shared__ float red[16][64];
  const int tid = threadIdx.x;
  // phase 1: two threads per (g,k), each sums 128 partial rows
  {
    const int half = tid >> 9;          // 0,1
    const int gk = tid & 511;           // (g,k)
    const float* P = partialsb + (size_t)gk;  // column gk of [512][256] viewed flat
    // partials layout: [g][b][256]; column index k = gk&255, g = gk>>8
    const int g = gk >> 8, k = gk & 255;
    const float* base = partialsb + (size_t)g * 256 * 256 + k;
    float s = 0.f;
    for (int b = half * 128; b < half * 128 + 128; ++b) s += base[(size_t)b * 256];
    (void)P;
    // combine two halves via LDS
    __shared__ float tmp[2][512];
    tmp[half][gk] = s;
    __syncthreads();
    if (half == 0) smacc[gk] = tmp[0][gk] + tmp[1][gk];
  }
  __syncthreads();
  // phase 2: j = tid&63, 16 parts x 32 k each
  const int j = tid & 63, part = tid >> 6;
  float acc = 0.f;
  for (int kk = 0; kk < 32; ++kk) {
    const int k = part * 32 + kk;
    acc += smacc[k] * W3[(size_t)j * 512 + k];
  }
  red[part][j] = acc;
  __syncthreads();
  if (part == 0) {
    float s = 0.f;
#pragma unroll
    for (int p = 0; p < 16; ++p) s += red[p][j];
    out[j] = b3[j] + s * invE;
  }
}

// -------- MFMA GEMM: C[n][o] = sum_k A[n][k]*W[o][k]; A,W,C bf16; O=256; batched via z --------
template <int K>
__global__ __launch_bounds__(256) void gemm_mfma_b_kernel(const u16* __restrict__ Ab,
                                                          const u16* __restrict__ WA,
                                                          const u16* __restrict__ WB,
                                                          u16* __restrict__ Cb, int N) {
  const int g = blockIdx.z;
  const u16* A = Ab + (size_t)g * NN * K;
  const u16* Wb = g ? WB : WA;
  u16* C = Cb + (size_t)g * NN * 256;
  const int lane = threadIdx.x & 63;
  const int w = threadIdx.x >> 6;
  const int wm = w >> 1, wn = w & 1;
  const int bn = blockIdx.x * 64 + wm * 32;
  const int bo = blockIdx.y * 64 + wn * 32;
  const int r0 = lane & 15;  // A-row / B-col within 16-tile
  const int kq = lane >> 4;  // k-quarter: 8 elems each
  const int ra0 = min(bn + r0, N - 1);
  const int ra1 = min(bn + 16 + r0, N - 1);
  const u16* a0p = &A[(size_t)ra0 * K + kq * 8];
  const u16* a1p = &A[(size_t)ra1 * K + kq * 8];
  const u16* b0p = &Wb[(size_t)(bo + r0) * K + kq * 8];
  const u16* b1p = &Wb[(size_t)(bo + 16 + r0) * K + kq * 8];
  f32x4 acc00 = {0.f, 0.f, 0.f, 0.f}, acc01 = {0.f, 0.f, 0.f, 0.f};
  f32x4 acc10 = {0.f, 0.f, 0.f, 0.f}, acc11 = {0.f, 0.f, 0.f, 0.f};
#pragma unroll
  for (int k0 = 0; k0 < K; k0 += 32) {
    const short8 a0 = *(const short8*)(a0p + k0);
    const short8 a1 = *(const short8*)(a1p + k0);
    const short8 b0 = *(const short8*)(b0p + k0);
    const short8 b1 = *(const short8*)(b1p + k0);
    acc00 = __builtin_amdgcn_mfma_f32_16x16x32_bf16(a0, b0, acc00, 0, 0, 0);
    acc01 = __builtin_amdgcn_mfma_f32_16x16x32_bf16(a0, b1, acc01, 0, 0, 0);
    acc10 = __builtin_amdgcn_mfma_f32_16x16x32_bf16(a1, b0, acc10, 0, 0, 0);
    acc11 = __builtin_amdgcn_mfma_f32_16x16x32_bf16(a1, b1, acc11, 0, 0, 0);
  }
  // D layout: row = 4*kq + r (within 16-tile), col = r0
#pragma unroll
  for (int r = 0; r < 4; ++r) {
    const int n0 = bn + 4 * kq + r;
    if (n0 < N) {
      C[(size_t)n0 * 256 + bo + r0] = (u16)(rne_bits(acc00[r]) >> 16);
      C[(size_t)n0 * 256 + bo + 16 + r0] = (u16)(rne_bits(acc01[r]) >> 16);
    }
    const int n1 = bn + 16 + 4 * kq + r;
    if (n1 < N) {
      C[(size_t)n1 * 256 + bo + r0] = (u16)(rne_bits(acc10[r]) >> 16);
      C[(size_t)n1 * 256 + bo + 16 + r0] = (u16)(rne_bits(acc11[r]) >> 16);
    }
  }
}

extern "C" void kernel_launch(void* const* d_in, const int* in_sizes, int n_in,
                              void* d_out, int out_size, void* d_ws, size_t ws_size,
                              hipStream_t stream) {
  const float* in1 = (const float*)d_in[0];
  const int* src1 = (const int*)d_in[1];
  const int* dst1 = (const int*)d_in[2];
  const float* in2 = (const float*)d_in[3];
  const int* src2 = (const int*)d_in[4];
  const int* dst2 = (const int*)d_in[5];
  const float* W11 = (const float*)d_in[6];
  const float* b11 = (const float*)d_in[7];
  const float* W12 = (const float*)d_in[8];
  const float* b12 = (const float*)d_in[9];
  const float* W21 = (const float*)d_in[10];
  const float* b21 = (const float*)d_in[11];
  const float* W22 = (const float*)d_in[12];
  const float* b22 = (const float*)d_in[13];
  const float* W3 = (const float*)d_in[14];
  const float* b3 = (const float*)d_in[15];
  const int E = in_sizes[1];
  const int N = NN;

  // ---- workspace carve (512B aligned) ----
  char* base = (char*)d_ws;
  size_t pos = 0;
  auto carve = [&](size_t bytes) -> char* {
    char* p = base + pos;
    pos = (pos + bytes + 511) & ~(size_t)511;
    return p;
  };
  int* degbase = (int*)carve((size_t)2 * 2 * N * sizeof(int));  // [g][deg|cursor]
  int* offb = (int*)carve((size_t)2 * N * sizeof(int));
  float* rdegb = (float*)carve((size_t)2 * N * sizeof(float));
  int* eid_sb = (int*)carve((size_t)2 * E * sizeof(int));
  int* esrc_sb = (int*)carve((size_t)2 * E * sizeof(int));
  u32* Hb = (u32*)carve((size_t)2 * N * 64 * sizeof(u32));     // h   (bf16, 128 feats)
  u32* H2b = (u32*)carve((size_t)2 * N * 64 * sizeof(u32));    // h2  (bf16, 128 feats)
  u32* Zb = (u32*)carve((size_t)2 * N * 128 * sizeof(u32));    // Z / Z2 (bf16, 256 feats)
  u32* HBb = (u32*)carve((size_t)2 * N * 128 * sizeof(u32));   // hB  (bf16, 256 feats)
  u32* H2Bb = (u32*)carve((size_t)2 * N * 128 * sizeof(u32));  // h2B (bf16, 256 feats)
  u16* Wa1 = (u16*)carve((size_t)32768 * sizeof(u16));         // W11 bf16
  u16* Wb1 = (u16*)carve((size_t)65536 * sizeof(u16));         // W12 bf16
  u16* Wa2 = (u16*)carve((size_t)32768 * sizeof(u16));         // W21 bf16
  u16* Wb2 = (u16*)carve((size_t)65536 * sizeof(u16));         // W22 bf16
  float* partialsb = (float*)carve((size_t)2 * 256 * 256 * sizeof(float));
  (void)ws_size; (void)n_in; (void)out_size;

  const int EB = (E + 255) / 256;  // edge-parallel blocks
  const int NB = N / 4;            // wave-per-node blocks (4 waves/block)
  const dim3 g2(EB, 2);
  const dim3 n2(NB, 2);
  const dim3 gemm_grid((N + 63) / 64, 4, 2);

  wconv_kernel<<<768, 256, 0, stream>>>(W11, W12, W21, W22, Wa1, Wb1, Wa2, Wb2, degbase);

  count_b_kernel<<<g2, 256, 0, stream>>>(dst1, dst2, degbase, E);
  scan_b_kernel<<<2, 1024, 0, stream>>>(degbase, offb, rdegb, N);
  fill_b_kernel<<<g2, 256, 0, stream>>>(src1, dst1, src2, dst2, offb, degbase, eid_sb, esrc_sb, E);

  // layer 1: h = segsum(inputs, dst)/deg ; h2 = segsum(h[src], dst) ; Z = h2 @ Wa.T
  gatherA_b_kernel<<<n2, 256, 0, stream>>>(in1, in2, eid_sb, offb, degbase, rdegb, Hb, E);
  gatherB_b_kernel<<<n2, 256, 0, stream>>>(Hb, esrc_sb, offb, degbase, H2b, E);
  gemm_mfma_b_kernel<128><<<gemm_grid, 256, 0, stream>>>((const u16*)H2b, Wa1, Wa2, (u16*)Zb, N);

  // layer 2 input: hB = rdeg * segsum(LR(0.5*(Z[src]+Z[dst])+ba), dst)
  passC_b_kernel<<<n2, 256, 0, stream>>>(Zb, esrc_sb, offb, degbase, rdegb, b11, b21, HBb, E);
  // h2B = segsum(hB[src], dst) ; Z2 = h2B @ Wb.T
  gatherC_b_kernel<<<n2, 256, 0, stream>>>(HBb, esrc_sb, offb, degbase, H2Bb, E);
  gemm_mfma_b_kernel<256><<<gemm_grid, 256, 0, stream>>>((const u16*)H2Bb, Wb1, Wb2, (u16*)Zb, N);

  // mean over edges of LR(0.5*(Z2[src]+Z2[dst])+bb)  (unscaled sum -> partials)
  passE_b_kernel<<<dim3(256, 2), 256, 0, stream>>>(Zb, esrc_sb, offb, degbase, b12, b22,
                                                   partialsb, N, E);
  final_fused_kernel<<<1, 1024, 0, stream>>>(partialsb, W3, b3, (float*)d_out, 1.0f / (float)E);
}